// Round 3
// baseline (1340.087 us; speedup 1.0000x reference)
//
#include <hip/hip_runtime.h>
#include <hip/hip_bf16.h>

typedef __hip_bfloat16 bf16;

// unsigned holds two bf16: low halfword = element 0, high halfword = element 1
__device__ __forceinline__ float2 bfpair(unsigned u){
  float2 r; r.x = __uint_as_float(u<<16); r.y = __uint_as_float(u & 0xffff0000u); return r;
}
// round-to-nearest-even f32 -> bf16 bits
__device__ __forceinline__ unsigned f2bf(float f){
  unsigned u = __float_as_uint(f);
  return (u + 0x7fffu + ((u>>16)&1u)) >> 16;
}
__device__ __forceinline__ unsigned fpack(float a, float b){
  return (f2bf(b)<<16) | f2bf(a);
}
// edge_index per reference is int64; harness may hand int32 or raw int64.
// int64 little-endian values < 2^31 have all-zero odd words. Random int32
// src values are nonzero whp -> false positive prob ~1e-14.
__device__ __forceinline__ int edge_is64(const int* e){
  return (e[1]==0) & (e[3]==0) & (e[5]==0);
}
__device__ __forceinline__ int edge_ld(const int* e, int is64, int idx){
  return e[is64 ? 2*idx : idx];
}

// ---------------- ratio = max ||x[:,3:6]|| ----------------
__global__ void k_ratio(const float* __restrict__ x, unsigned* __restrict__ ratio, int N){
  int i = blockIdx.x*blockDim.x + threadIdx.x;
  int stride = gridDim.x*blockDim.x;
  float m = 0.f;
  for(; i<N; i+=stride){
    float a = x[(size_t)i*12+3];
    float b = x[(size_t)i*12+4];
    float c = x[(size_t)i*12+5];
    m = fmaxf(m, sqrtf(a*a+b*b+c*c));
  }
  #pragma unroll
  for(int off=1; off<64; off<<=1) m = fmaxf(m, __shfl_xor(m, off));
  if((threadIdx.x & 63)==0) atomicMax(ratio, __float_as_uint(m)); // all vals >= 0
}

// ---------------- degree histogram ----------------
__global__ void k_degree(const int* __restrict__ eidx, int* __restrict__ deg, int E, int N){
  int e = blockIdx.x*blockDim.x + threadIdx.x;
  if(e>=E) return;
  int is64 = edge_is64(eidx);
  int d = edge_ld(eidx, is64, E+e);
  if((unsigned)d < (unsigned)N) atomicAdd(&deg[d], 1);
}

// ---------------- 3-kernel exclusive scan over deg[N] ----------------
__global__ void k_scan1(const int* __restrict__ deg, int* __restrict__ bsum, int N){
  int t = threadIdx.x;
  int idx0 = blockIdx.x*1024 + t*4;
  int s=0;
  #pragma unroll
  for(int i=0;i<4;i++){ int idx=idx0+i; if(idx<N) s += deg[idx]; }
  #pragma unroll
  for(int off=1; off<64; off<<=1) s += __shfl_xor(s, off);
  __shared__ int ws4[4];
  if((t&63)==0) ws4[t>>6]=s;
  __syncthreads();
  if(t==0) bsum[blockIdx.x]=ws4[0]+ws4[1]+ws4[2]+ws4[3];
}
__global__ void k_scan2(int* bsum, int nb){
  if(threadIdx.x==0 && blockIdx.x==0){
    int acc=0;
    for(int i=0;i<nb;i++){ int v=bsum[i]; bsum[i]=acc; acc+=v; }
  }
}
__global__ void k_scan3(const int* __restrict__ deg, const int* __restrict__ bsum,
                        int* __restrict__ offs, int* __restrict__ pos,
                        float* __restrict__ invdeg, int N, int E){
  int t = threadIdx.x;
  int idx0 = blockIdx.x*1024 + t*4;
  int d[4]; int s=0;
  #pragma unroll
  for(int i=0;i<4;i++){ int idx=idx0+i; d[i] = (idx<N)? deg[idx]:0; s+=d[i]; }
  int lane=t&63, w=t>>6;
  int incl=s;
  #pragma unroll
  for(int off=1; off<64; off<<=1){ int v=__shfl_up(incl, (unsigned)off); if(lane>=off) incl+=v; }
  __shared__ int wsum[4];
  if(lane==63) wsum[w]=incl;
  __syncthreads();
  int base = bsum[blockIdx.x];
  for(int i=0;i<w;i++) base += wsum[i];
  int run = base + incl - s;
  #pragma unroll
  for(int i=0;i<4;i++){
    int idx=idx0+i;
    if(idx<N){
      offs[idx]=run; pos[idx]=run;
      invdeg[idx] = 1.0f / (float)(d[i]>0? d[i]:1);
    }
    run += d[i];
  }
  if(blockIdx.x==0 && t==0) offs[N]=E;
}

// ---------------- bucket edges into CSR ----------------
__global__ void k_bucket(const int* __restrict__ eidx, int* __restrict__ pos,
                         int* __restrict__ csr, int E, int N){
  int e = blockIdx.x*blockDim.x + threadIdx.x;
  if(e>=E) return;
  int is64 = edge_is64(eidx);
  int d = edge_ld(eidx, is64, E+e);
  int s = edge_ld(eidx, is64, e);
  if((unsigned)d >= (unsigned)N) return;
  if((unsigned)s >= (unsigned)N) s = 0;
  int p = atomicAdd(&pos[d], 1);
  if((unsigned)p < (unsigned)E) csr[p] = s;   // clamp: never write OOB
}

// ---------------- encoder: h = relu(x@W1+b1)@W2+b2 -> bf16 ----------------
__global__ __launch_bounds__(256) void k_encoder(
  const float* __restrict__ x,
  const float* __restrict__ W1, const float* __restrict__ b1,
  const float* __restrict__ W2, const float* __restrict__ b2,
  bf16* __restrict__ h, int N)
{
  __shared__ float Xs[64][12];
  __shared__ float W1s[12][128];
  __shared__ float T1[64][128];
  __shared__ float Bs[16][128];
  __shared__ float b1s[128];
  int tid = threadIdx.x;
  int tx = tid & 31, ty = tid >> 5;
  int rowBase = blockIdx.x*64;
  for(int idx=tid; idx<768; idx+=256){
    int r = idx/12, c = idx - r*12;
    int row = rowBase + r;
    Xs[r][c] = (row<N)? x[(size_t)row*12+c] : 0.f;
  }
  for(int idx=tid; idx<1536; idx+=256) W1s[idx>>7][idx&127] = W1[idx];
  if(tid<128) b1s[tid] = b1[tid];
  __syncthreads();
  float acc[8][4] = {};
  #pragma unroll
  for(int k=0;k<12;k++){
    float4 w4 = *(float4*)&W1s[k][tx*4];
    #pragma unroll
    for(int r=0;r<8;r++){
      float a = Xs[ty*8+r][k];
      acc[r][0]+=a*w4.x; acc[r][1]+=a*w4.y; acc[r][2]+=a*w4.z; acc[r][3]+=a*w4.w;
    }
  }
  #pragma unroll
  for(int r=0;r<8;r++)
    #pragma unroll
    for(int c=0;c<4;c++)
      T1[ty*8+r][tx*4+c] = fmaxf(acc[r][c] + b1s[tx*4+c], 0.f);
  __syncthreads();
  float acc2[8][4] = {};
  int bk = tid>>4, bc = (tid&15)*8;
  for(int kt=0;kt<8;kt++){
    int k = kt*16 + bk;
    float4 w0 = *(const float4*)(W2 + (size_t)k*128 + bc);
    float4 w1 = *(const float4*)(W2 + (size_t)k*128 + bc + 4);
    *(float4*)&Bs[bk][bc]   = w0;
    *(float4*)&Bs[bk][bc+4] = w1;
    __syncthreads();
    #pragma unroll
    for(int kk=0;kk<16;kk++){
      float4 b4 = *(float4*)&Bs[kk][tx*4];
      #pragma unroll
      for(int r=0;r<8;r++){
        float a = T1[ty*8+r][kt*16+kk];
        acc2[r][0]+=a*b4.x; acc2[r][1]+=a*b4.y; acc2[r][2]+=a*b4.z; acc2[r][3]+=a*b4.w;
      }
    }
    __syncthreads();
  }
  #pragma unroll
  for(int r=0;r<8;r++){
    int row = rowBase + ty*8 + r;
    if(row<N){
      float o0 = acc2[r][0] + b2[tx*4+0];
      float o1 = acc2[r][1] + b2[tx*4+1];
      float o2 = acc2[r][2] + b2[tx*4+2];
      float o3 = acc2[r][3] + b2[tx*4+3];
      uint2 o; o.x = fpack(o0,o1); o.y = fpack(o2,o3);
      *(uint2*)(h + (size_t)row*128 + tx*4) = o;
    }
  }
}

// ---------------- SAGE layer: fused mean-aggr + GEMM + LN + residual-ReLU ------
// reads hin (bf16), writes hout (bf16). Double-buffered: no cross-block race.
__global__ __launch_bounds__(256) void k_sage(
    const bf16* __restrict__ hin, bf16* __restrict__ hout,
    const int* __restrict__ offs, const int* __restrict__ csr,
    const float* __restrict__ invdeg,
    const float* __restrict__ Wl, const float* __restrict__ bl,
    const float* __restrict__ Wr, const float* __restrict__ lng,
    const float* __restrict__ lnb, int N, int E)
{
  __shared__ float Ag[64][128];   // mean-aggregated neighbor features, fp32
  __shared__ float As[64][16];
  __shared__ float Bs[16][128];
  int tid = threadIdx.x;
  int lane = tid & 63, wv = tid >> 6;
  int rowBase = blockIdx.x*64;

  // --- aggregation phase: wave wv handles rows wv*16 .. wv*16+15 ---
  for(int rr=0; rr<16; ++rr){
    int r = wv*16 + rr;
    int row = rowBase + r;
    float ax=0.f, ay=0.f;
    if(row < N){
      int s = offs[row], e = offs[row+1];
      s = max(0, min(s, E)); e = max(s, min(e, E));   // clamp: finite even if scan broke
      for(int i=s;i<e;i++){
        int j = csr[i];
        if((unsigned)j >= (unsigned)N) j = 0;          // clamp: no wild reads
        float2 v = bfpair(*(const unsigned*)(hin + (size_t)j*128 + lane*2));
        ax += v.x; ay += v.y;
      }
      float id = invdeg[row];
      ax *= id; ay *= id;
    }
    Ag[r][lane*2]   = ax;
    Ag[r][lane*2+1] = ay;
  }
  __syncthreads();

  // --- GEMM phase: y = [Ag | hin] @ [Wl ; Wr], K = 256 ---
  int tx = tid & 31, ty = tid >> 5;
  int ar = tid >> 2, akq = (tid & 3)*4;
  int bk = tid >> 4, bc = (tid & 15)*8;
  int arow = rowBase + ar;
  float acc[8][4] = {};
  for(int kt=0; kt<16; ++kt){
    if(kt>=8){
      int k0 = (kt-8)*16 + akq;
      float4 av = make_float4(0.f,0.f,0.f,0.f);
      if(arow < N){
        uint2 raw = *(const uint2*)(hin + (size_t)arow*128 + k0);
        float2 f0=bfpair(raw.x), f1=bfpair(raw.y);
        av = make_float4(f0.x,f0.y,f1.x,f1.y);
      }
      *(float4*)&As[ar][akq] = av;
    }
    int k = kt*16 + bk;
    const float* wsrc = (k < 128) ? (Wl + (size_t)k*128 + bc) : (Wr + (size_t)(k-128)*128 + bc);
    float4 w0 = *(const float4*)wsrc;
    float4 w1 = *(const float4*)(wsrc + 4);
    *(float4*)&Bs[bk][bc]   = w0;
    *(float4*)&Bs[bk][bc+4] = w1;
    __syncthreads();
    if(kt < 8){
      #pragma unroll
      for(int kk=0;kk<16;kk++){
        float4 b4 = *(float4*)&Bs[kk][tx*4];
        #pragma unroll
        for(int r=0;r<8;r++){
          float a = Ag[ty*8+r][kt*16+kk];
          acc[r][0]+=a*b4.x; acc[r][1]+=a*b4.y; acc[r][2]+=a*b4.z; acc[r][3]+=a*b4.w;
        }
      }
    } else {
      #pragma unroll
      for(int kk=0;kk<16;kk++){
        float4 b4 = *(float4*)&Bs[kk][tx*4];
        #pragma unroll
        for(int r=0;r<8;r++){
          float a = As[ty*8+r][kk];
          acc[r][0]+=a*b4.x; acc[r][1]+=a*b4.y; acc[r][2]+=a*b4.z; acc[r][3]+=a*b4.w;
        }
      }
    }
    __syncthreads();
  }

  // --- epilogue: bias, LayerNorm (32-lane row reduce), residual-ReLU ---
  int col0 = tx*4;
  float blv[4], gv[4], bv[4];
  #pragma unroll
  for(int c=0;c<4;c++){ blv[c]=bl[col0+c]; gv[c]=lng[col0+c]; bv[c]=lnb[col0+c]; }
  #pragma unroll
  for(int r=0;r<8;r++){
    int row = rowBase + ty*8 + r;
    float s=0.f, q=0.f;
    #pragma unroll
    for(int c=0;c<4;c++){ float v = acc[r][c]+blv[c]; acc[r][c]=v; s+=v; q+=v*v; }
    #pragma unroll
    for(int off=1; off<32; off<<=1){ s += __shfl_xor(s, off, 32); q += __shfl_xor(q, off, 32); }
    float mu = s*(1.f/128.f);
    float var = fmaxf(q*(1.f/128.f) - mu*mu, 0.f);
    float rstd = rsqrtf(var + 1e-5f);
    if(row < N){
      uint2 hraw = *(const uint2*)(hin + (size_t)row*128 + col0);
      float2 h01 = bfpair(hraw.x), h23 = bfpair(hraw.y);
      float hv[4] = {h01.x, h01.y, h23.x, h23.y};
      float ov[4];
      #pragma unroll
      for(int c=0;c<4;c++){
        float y = (acc[r][c]-mu)*rstd*gv[c] + bv[c];
        ov[c] = hv[c] + fmaxf(y, 0.f);
      }
      uint2 o; o.x = fpack(ov[0],ov[1]); o.y = fpack(ov[2],ov[3]);
      *(uint2*)(hout + (size_t)row*128 + col0) = o;
    }
  }
}

// ---------------- fused heads: out[:,0:3]=disp*ratio, out[:,3]=stress*ratio --------
__global__ __launch_bounds__(256) void k_heads(
  const bf16* __restrict__ h,
  const float* __restrict__ dW1, const float* __restrict__ db1,
  const float* __restrict__ dW2, const float* __restrict__ db2,
  const float* __restrict__ dW3, const float* __restrict__ db3,
  const float* __restrict__ sW1, const float* __restrict__ sb1,
  const float* __restrict__ sW2, const float* __restrict__ sb2,
  const float* __restrict__ sW3, const float* __restrict__ sb3,
  const float* __restrict__ ratio_p, float* __restrict__ out, int N)
{
  __shared__ float T1[64][132];   // +4 pad for K-major read phase
  __shared__ float T2[64][68];
  __shared__ float As[64][16];
  __shared__ float Bs[16][128];
  const float ratio = *ratio_p;
  int tid = threadIdx.x;
  int tx = tid & 31, ty = tid >> 5;
  int rowBase = blockIdx.x * 64;
  int ar = tid >> 2, akq = (tid & 3)*4;
  int bk = tid >> 4, bc = (tid & 15)*8;
  int ty2 = tid >> 4, tx2 = tid & 15;

  for(int head=0; head<2; head++){
    const float* W1h = head? sW1 : dW1;
    const float* b1h = head? sb1 : db1;
    const float* W2h = head? sW2 : dW2;
    const float* b2h = head? sb2 : db2;
    const float* W3h = head? sW3 : dW3;
    const float* b3h = head? sb3 : db3;

    // stage 1: T1 = relu(h @ W1h + b1h)   [64][128], K=128
    float acc[8][4] = {};
    for(int kt=0; kt<8; ++kt){
      int k0 = kt*16 + akq;
      int arow = rowBase + ar;
      float4 av = make_float4(0.f,0.f,0.f,0.f);
      if(arow < N){
        uint2 raw = *(const uint2*)(h + (size_t)arow*128 + k0);
        float2 f0=bfpair(raw.x), f1=bfpair(raw.y);
        av = make_float4(f0.x,f0.y,f1.x,f1.y);
      }
      *(float4*)&As[ar][akq] = av;
      int k = kt*16 + bk;
      float4 w0 = *(const float4*)(W1h + (size_t)k*128 + bc);
      float4 w1 = *(const float4*)(W1h + (size_t)k*128 + bc + 4);
      *(float4*)&Bs[bk][bc]   = w0;
      *(float4*)&Bs[bk][bc+4] = w1;
      __syncthreads();
      #pragma unroll
      for(int kk=0;kk<16;kk++){
        float4 b4 = *(float4*)&Bs[kk][tx*4];
        #pragma unroll
        for(int r=0;r<8;r++){
          float a = As[ty*8+r][kk];
          acc[r][0]+=a*b4.x; acc[r][1]+=a*b4.y; acc[r][2]+=a*b4.z; acc[r][3]+=a*b4.w;
        }
      }
      __syncthreads();
    }
    float b1v[4];
    #pragma unroll
    for(int c=0;c<4;c++) b1v[c] = b1h[tx*4+c];
    #pragma unroll
    for(int r=0;r<8;r++)
      #pragma unroll
      for(int c=0;c<4;c++)
        T1[ty*8+r][tx*4+c] = fmaxf(acc[r][c] + b1v[c], 0.f);
    __syncthreads();

    // stage 2: T2 = relu(T1 @ W2h + b2h)  [64][64], K=128
    float acc2[4][4] = {};
    for(int k=0;k<128;k++){
      float4 g4 = *(const float4*)(W2h + (size_t)k*64 + tx2*4);
      #pragma unroll
      for(int j=0;j<4;j++){
        float a = T1[ty2*4+j][k];
        acc2[j][0]+=a*g4.x; acc2[j][1]+=a*g4.y; acc2[j][2]+=a*g4.z; acc2[j][3]+=a*g4.w;
      }
    }
    float b2v[4];
    #pragma unroll
    for(int c=0;c<4;c++) b2v[c] = b2h[tx2*4+c];
    #pragma unroll
    for(int j=0;j<4;j++)
      #pragma unroll
      for(int c=0;c<4;c++)
        T2[ty2*4+j][tx2*4+c] = fmaxf(acc2[j][c]+b2v[c], 0.f);
    __syncthreads();

    // stage 3: tiny final matmul + scale + store
    if(head==0){
      if(tid < 192){
        int n = tid/3, c = tid - n*3;
        float s = b3h[c];
        for(int k=0;k<64;k++) s += T2[n][k]*W3h[k*3+c];
        int row = rowBase + n;
        if(row < N) out[(size_t)row*4 + c] = s*ratio;
      }
    } else {
      if(tid < 64){
        int n = tid;
        float s = b3h[0];
        for(int k=0;k<64;k++) s += T2[n][k]*W3h[k];
        int row = rowBase + n;
        if(row < N) out[(size_t)row*4 + 3] = s*ratio;
      }
    }
    __syncthreads();
  }
}

extern "C" void kernel_launch(void* const* d_in, const int* in_sizes, int n_in,
                              void* d_out, int out_size, void* d_ws, size_t ws_size,
                              hipStream_t stream)
{
  const float* x   = (const float*)d_in[0];
  const int*  eidx = (const int*) d_in[1];
  const float* eW1 = (const float*)d_in[2];
  const float* eb1 = (const float*)d_in[3];
  const float* eW2 = (const float*)d_in[4];
  const float* eb2 = (const float*)d_in[5];
  const float* llW = (const float*)d_in[6];
  const float* llb = (const float*)d_in[7];
  const float* lrW = (const float*)d_in[8];
  const float* lng = (const float*)d_in[9];
  const float* lnb = (const float*)d_in[10];
  const float* dW1 = (const float*)d_in[11];
  const float* db1 = (const float*)d_in[12];
  const float* dW2 = (const float*)d_in[13];
  const float* db2 = (const float*)d_in[14];
  const float* dW3 = (const float*)d_in[15];
  const float* db3 = (const float*)d_in[16];
  const float* sW1 = (const float*)d_in[17];
  const float* sb1 = (const float*)d_in[18];
  const float* sW2 = (const float*)d_in[19];
  const float* sb2 = (const float*)d_in[20];
  const float* sW3 = (const float*)d_in[21];
  const float* sb3 = (const float*)d_in[22];
  float* out = (float*)d_out;

  const int N = in_sizes[0] / 12;
  const int E = in_sizes[1] / 2;
  (void)n_in; (void)out_size; (void)ws_size;

  // workspace layout (256B aligned slots) — total ~29 MB
  char* base = (char*)d_ws;
  size_t off = 0;
  auto alloc = [&](size_t nbytes)->char*{
    char* p = base + off; off += (nbytes + 255) & ~(size_t)255; return p;
  };
  unsigned* ratio = (unsigned*)alloc(4);
  int*   deg    = (int*)  alloc((size_t)N*4);
  int*   offs   = (int*)  alloc(((size_t)N+1)*4);
  int*   pos    = (int*)  alloc((size_t)N*4);
  int*   bsum   = (int*)  alloc(256*4);
  int*   csr    = (int*)  alloc((size_t)E*4);
  float* invdeg = (float*)alloc((size_t)N*4);
  bf16*  hA     = (bf16*) alloc((size_t)N*128*2);
  bf16*  hB     = (bf16*) alloc((size_t)N*128*2);

  size_t zbytes = (size_t)((char*)offs - base);   // zero ratio + deg
  hipMemsetAsync(d_ws, 0, zbytes, stream);

  int nbE    = (E + 255)/256;
  int nbScan = (N + 1023)/1024;
  int nbTile = (N + 63)/64;

  k_ratio <<<256, 256, 0, stream>>>(x, ratio, N);
  k_degree<<<nbE, 256, 0, stream>>>(eidx, deg, E, N);
  k_scan1 <<<nbScan, 256, 0, stream>>>(deg, bsum, N);
  k_scan2 <<<1, 64, 0, stream>>>(bsum, nbScan);
  k_scan3 <<<nbScan, 256, 0, stream>>>(deg, bsum, offs, pos, invdeg, N, E);
  k_bucket<<<nbE, 256, 0, stream>>>(eidx, pos, csr, E, N);

  k_encoder<<<nbTile, 256, 0, stream>>>(x, eW1, eb1, eW2, eb2, hA, N);
  bf16* hin = hA; bf16* hout = hB;
  for(int l=0;l<4;l++){
    k_sage<<<nbTile, 256, 0, stream>>>(hin, hout, offs, csr, invdeg,
        llW + (size_t)l*128*128, llb + (size_t)l*128,
        lrW + (size_t)l*128*128, lng + (size_t)l*128, lnb + (size_t)l*128, N, E);
    bf16* t = hin; hin = hout; hout = t;
  }
  // after 4 swaps, final h is in hin (hA)
  k_heads<<<nbTile, 256, 0, stream>>>(hin, dW1, db1, dW2, db2, dW3, db3,
      sW1, sb1, sW2, sb2, sW3, sb3, (const float*)ratio, out, N);
}

// Round 4
// 682.056 us; speedup vs baseline: 1.9648x; 1.9648x over previous
//
#include <hip/hip_runtime.h>
#include <hip/hip_bf16.h>

typedef __hip_bfloat16 bf16;

// unsigned holds two bf16: low halfword = element 0, high halfword = element 1
__device__ __forceinline__ float2 bfpair(unsigned u){
  float2 r; r.x = __uint_as_float(u<<16); r.y = __uint_as_float(u & 0xffff0000u); return r;
}
// round-to-nearest-even f32 -> bf16 bits
__device__ __forceinline__ unsigned f2bf(float f){
  unsigned u = __float_as_uint(f);
  return (u + 0x7fffu + ((u>>16)&1u)) >> 16;
}
__device__ __forceinline__ unsigned fpack(float a, float b){
  return (f2bf(b)<<16) | f2bf(a);
}
// edge_index per reference is int64; detect layout (verified working in R3)
__device__ __forceinline__ int edge_is64(const int* e){
  return (e[1]==0) & (e[3]==0) & (e[5]==0);
}
__device__ __forceinline__ int edge_ld(const int* e, int is64, int idx){
  return e[is64 ? 2*idx : idx];
}

// ---------------- ratio = max ||x[:,3:6]|| ----------------
__global__ void k_ratio(const float* __restrict__ x, unsigned* __restrict__ ratio, int N){
  int i = blockIdx.x*blockDim.x + threadIdx.x;
  int stride = gridDim.x*blockDim.x;
  float m = 0.f;
  for(; i<N; i+=stride){
    float a = x[(size_t)i*12+3];
    float b = x[(size_t)i*12+4];
    float c = x[(size_t)i*12+5];
    m = fmaxf(m, sqrtf(a*a+b*b+c*c));
  }
  #pragma unroll
  for(int off=1; off<64; off<<=1) m = fmaxf(m, __shfl_xor(m, off));
  if((threadIdx.x & 63)==0) atomicMax(ratio, __float_as_uint(m));
}

// ---------------- degree histogram ----------------
__global__ void k_degree(const int* __restrict__ eidx, int* __restrict__ deg, int E, int N){
  int e = blockIdx.x*blockDim.x + threadIdx.x;
  if(e>=E) return;
  int is64 = edge_is64(eidx);
  int d = edge_ld(eidx, is64, E+e);
  if((unsigned)d < (unsigned)N) atomicAdd(&deg[d], 1);
}

// ---------------- 3-kernel exclusive scan over deg[N] ----------------
__global__ void k_scan1(const int* __restrict__ deg, int* __restrict__ bsum, int N){
  int t = threadIdx.x;
  int idx0 = blockIdx.x*1024 + t*4;
  int s=0;
  #pragma unroll
  for(int i=0;i<4;i++){ int idx=idx0+i; if(idx<N) s += deg[idx]; }
  #pragma unroll
  for(int off=1; off<64; off<<=1) s += __shfl_xor(s, off);
  __shared__ int ws4[4];
  if((t&63)==0) ws4[t>>6]=s;
  __syncthreads();
  if(t==0) bsum[blockIdx.x]=ws4[0]+ws4[1]+ws4[2]+ws4[3];
}
__global__ void k_scan2(int* bsum, int nb){
  if(threadIdx.x==0 && blockIdx.x==0){
    int acc=0;
    for(int i=0;i<nb;i++){ int v=bsum[i]; bsum[i]=acc; acc+=v; }
  }
}
__global__ void k_scan3(const int* __restrict__ deg, const int* __restrict__ bsum,
                        int* __restrict__ offs, int* __restrict__ pos,
                        float* __restrict__ invdeg, int N, int E){
  int t = threadIdx.x;
  int idx0 = blockIdx.x*1024 + t*4;
  int d[4]; int s=0;
  #pragma unroll
  for(int i=0;i<4;i++){ int idx=idx0+i; d[i] = (idx<N)? deg[idx]:0; s+=d[i]; }
  int lane=t&63, w=t>>6;
  int incl=s;
  #pragma unroll
  for(int off=1; off<64; off<<=1){ int v=__shfl_up(incl, (unsigned)off); if(lane>=off) incl+=v; }
  __shared__ int wsum[4];
  if(lane==63) wsum[w]=incl;
  __syncthreads();
  int base = bsum[blockIdx.x];
  for(int i=0;i<w;i++) base += wsum[i];
  int run = base + incl - s;
  #pragma unroll
  for(int i=0;i<4;i++){
    int idx=idx0+i;
    if(idx<N){
      offs[idx]=run; pos[idx]=run;
      invdeg[idx] = 1.0f / (float)(d[i]>0? d[i]:1);
    }
    run += d[i];
  }
  if(blockIdx.x==0 && t==0) offs[N]=E;
}

// ---------------- bucket edges into CSR ----------------
__global__ void k_bucket(const int* __restrict__ eidx, int* __restrict__ pos,
                         int* __restrict__ csr, int E, int N){
  int e = blockIdx.x*blockDim.x + threadIdx.x;
  if(e>=E) return;
  int is64 = edge_is64(eidx);
  int d = edge_ld(eidx, is64, E+e);
  int s = edge_ld(eidx, is64, e);
  if((unsigned)d >= (unsigned)N) return;
  if((unsigned)s >= (unsigned)N) s = 0;
  int p = atomicAdd(&pos[d], 1);
  if((unsigned)p < (unsigned)E) csr[p] = s;
}

// ---------------- mean aggregation: half-wave (32 lanes) per dst row ----------------
// lane reads uint2 = 4 bf16 = 8 B; 32 lanes cover the 256 B row. 2 rows/wave,
// 8 rows/block -> 6250 blocks, ~25k waves: latency hidden by TLP + 4x unroll MLP.
__global__ __launch_bounds__(256) void k_aggregate(
    const bf16* __restrict__ h, bf16* __restrict__ agg,
    const int* __restrict__ offs, const int* __restrict__ csr,
    const float* __restrict__ invdeg, int N, int E){
  int row = blockIdx.x*8 + (threadIdx.x>>5);
  int l = threadIdx.x & 31;
  if(row >= N) return;
  int s = offs[row], e = offs[row+1];
  s = max(0, min(s, E)); e = max(s, min(e, E));
  float a0=0.f, a1=0.f, a2=0.f, a3=0.f;
  int i = s;
  for(; i+4<=e; i+=4){
    int j0=csr[i], j1=csr[i+1], j2=csr[i+2], j3=csr[i+3];
    uint2 u0 = *(const uint2*)(h + (size_t)j0*128 + l*4);
    uint2 u1 = *(const uint2*)(h + (size_t)j1*128 + l*4);
    uint2 u2 = *(const uint2*)(h + (size_t)j2*128 + l*4);
    uint2 u3 = *(const uint2*)(h + (size_t)j3*128 + l*4);
    float2 p0=bfpair(u0.x), q0=bfpair(u0.y);
    float2 p1=bfpair(u1.x), q1=bfpair(u1.y);
    float2 p2=bfpair(u2.x), q2=bfpair(u2.y);
    float2 p3=bfpair(u3.x), q3=bfpair(u3.y);
    a0 += p0.x+p1.x+p2.x+p3.x;
    a1 += p0.y+p1.y+p2.y+p3.y;
    a2 += q0.x+q1.x+q2.x+q3.x;
    a3 += q0.y+q1.y+q2.y+q3.y;
  }
  for(; i<e; ++i){
    int j = csr[i];
    uint2 u = *(const uint2*)(h + (size_t)j*128 + l*4);
    float2 p=bfpair(u.x), q=bfpair(u.y);
    a0+=p.x; a1+=p.y; a2+=q.x; a3+=q.y;
  }
  float id = invdeg[row];
  uint2 o; o.x = fpack(a0*id, a1*id); o.y = fpack(a2*id, a3*id);
  *(uint2*)(agg + (size_t)row*128 + l*4) = o;
}

// ---------------- encoder: h = relu(x@W1+b1)@W2+b2 -> bf16 ----------------
__global__ __launch_bounds__(256) void k_encoder(
  const float* __restrict__ x,
  const float* __restrict__ W1, const float* __restrict__ b1,
  const float* __restrict__ W2, const float* __restrict__ b2,
  bf16* __restrict__ h, int N)
{
  __shared__ float Xs[64][12];
  __shared__ float W1s[12][128];
  __shared__ float T1[64][128];
  __shared__ float Bs[16][128];
  __shared__ float b1s[128];
  int tid = threadIdx.x;
  int tx = tid & 31, ty = tid >> 5;
  int rowBase = blockIdx.x*64;
  for(int idx=tid; idx<768; idx+=256){
    int r = idx/12, c = idx - r*12;
    int row = rowBase + r;
    Xs[r][c] = (row<N)? x[(size_t)row*12+c] : 0.f;
  }
  for(int idx=tid; idx<1536; idx+=256) W1s[idx>>7][idx&127] = W1[idx];
  if(tid<128) b1s[tid] = b1[tid];
  __syncthreads();
  float acc[8][4] = {};
  #pragma unroll
  for(int k=0;k<12;k++){
    float4 w4 = *(float4*)&W1s[k][tx*4];
    #pragma unroll
    for(int r=0;r<8;r++){
      float a = Xs[ty*8+r][k];
      acc[r][0]+=a*w4.x; acc[r][1]+=a*w4.y; acc[r][2]+=a*w4.z; acc[r][3]+=a*w4.w;
    }
  }
  #pragma unroll
  for(int r=0;r<8;r++)
    #pragma unroll
    for(int c=0;c<4;c++)
      T1[ty*8+r][tx*4+c] = fmaxf(acc[r][c] + b1s[tx*4+c], 0.f);
  __syncthreads();
  float acc2[8][4] = {};
  int bk = tid>>4, bc = (tid&15)*8;
  for(int kt=0;kt<8;kt++){
    int k = kt*16 + bk;
    float4 w0 = *(const float4*)(W2 + (size_t)k*128 + bc);
    float4 w1 = *(const float4*)(W2 + (size_t)k*128 + bc + 4);
    *(float4*)&Bs[bk][bc]   = w0;
    *(float4*)&Bs[bk][bc+4] = w1;
    __syncthreads();
    #pragma unroll
    for(int kk=0;kk<16;kk++){
      float4 b4 = *(float4*)&Bs[kk][tx*4];
      #pragma unroll
      for(int r=0;r<8;r++){
        float a = T1[ty*8+r][kt*16+kk];
        acc2[r][0]+=a*b4.x; acc2[r][1]+=a*b4.y; acc2[r][2]+=a*b4.z; acc2[r][3]+=a*b4.w;
      }
    }
    __syncthreads();
  }
  #pragma unroll
  for(int r=0;r<8;r++){
    int row = rowBase + ty*8 + r;
    if(row<N){
      float o0 = acc2[r][0] + b2[tx*4+0];
      float o1 = acc2[r][1] + b2[tx*4+1];
      float o2 = acc2[r][2] + b2[tx*4+2];
      float o3 = acc2[r][3] + b2[tx*4+3];
      uint2 o; o.x = fpack(o0,o1); o.y = fpack(o2,o3);
      *(uint2*)(h + (size_t)row*128 + tx*4) = o;
    }
  }
}

// ---------------- SAGE layer GEMM: y=[agg|h]@[Wl;Wr]+bl; LN; h+=relu(y) (in place) --
// Aggregation already done -> each block touches only its own 64 rows of h.
__global__ __launch_bounds__(256) void k_sage(
    bf16* __restrict__ h, const bf16* __restrict__ agg,
    const float* __restrict__ Wl, const float* __restrict__ bl,
    const float* __restrict__ Wr, const float* __restrict__ lng,
    const float* __restrict__ lnb, int N)
{
  __shared__ float As[64][16];
  __shared__ float Bs[16][128];
  int tid = threadIdx.x;
  int tx = tid & 31, ty = tid >> 5;
  int ar = tid >> 2, akq = (tid & 3)*4;
  int bk = tid >> 4, bc = (tid & 15)*8;
  int rowBase = blockIdx.x*64;
  int arow = rowBase + ar;
  float acc[8][4] = {};
  for(int kt=0; kt<16; ++kt){
    // stage A-slice [64][16] from agg (kt<8) or h (kt>=8), bf16 -> fp32
    {
      int k0 = (kt & 7)*16 + akq;
      const bf16* asrc = (kt < 8) ? agg : h;
      float4 av = make_float4(0.f,0.f,0.f,0.f);
      if(arow < N){
        uint2 raw = *(const uint2*)(asrc + (size_t)arow*128 + k0);
        float2 f0=bfpair(raw.x), f1=bfpair(raw.y);
        av = make_float4(f0.x,f0.y,f1.x,f1.y);
      }
      *(float4*)&As[ar][akq] = av;
    }
    int k = kt*16 + bk;
    const float* wsrc = (k < 128) ? (Wl + (size_t)k*128 + bc) : (Wr + (size_t)(k-128)*128 + bc);
    float4 w0 = *(const float4*)wsrc;
    float4 w1 = *(const float4*)(wsrc + 4);
    *(float4*)&Bs[bk][bc]   = w0;
    *(float4*)&Bs[bk][bc+4] = w1;
    __syncthreads();
    #pragma unroll
    for(int kk=0;kk<16;kk++){
      float4 b4 = *(float4*)&Bs[kk][tx*4];
      #pragma unroll
      for(int r=0;r<8;r++){
        float a = As[ty*8+r][kk];
        acc[r][0]+=a*b4.x; acc[r][1]+=a*b4.y; acc[r][2]+=a*b4.z; acc[r][3]+=a*b4.w;
      }
    }
    __syncthreads();
  }

  // epilogue: bias, LayerNorm (32-lane row reduce), residual-ReLU, in-place store
  int col0 = tx*4;
  float blv[4], gv[4], bv[4];
  #pragma unroll
  for(int c=0;c<4;c++){ blv[c]=bl[col0+c]; gv[c]=lng[col0+c]; bv[c]=lnb[col0+c]; }
  #pragma unroll
  for(int r=0;r<8;r++){
    int row = rowBase + ty*8 + r;
    float s=0.f, q=0.f;
    #pragma unroll
    for(int c=0;c<4;c++){ float v = acc[r][c]+blv[c]; acc[r][c]=v; s+=v; q+=v*v; }
    #pragma unroll
    for(int off=1; off<32; off<<=1){ s += __shfl_xor(s, off, 32); q += __shfl_xor(q, off, 32); }
    float mu = s*(1.f/128.f);
    float var = fmaxf(q*(1.f/128.f) - mu*mu, 0.f);
    float rstd = rsqrtf(var + 1e-5f);
    if(row < N){
      uint2 hraw = *(const uint2*)(h + (size_t)row*128 + col0);
      float2 h01 = bfpair(hraw.x), h23 = bfpair(hraw.y);
      float hv[4] = {h01.x, h01.y, h23.x, h23.y};
      float ov[4];
      #pragma unroll
      for(int c=0;c<4;c++){
        float y = (acc[r][c]-mu)*rstd*gv[c] + bv[c];
        ov[c] = hv[c] + fmaxf(y, 0.f);
      }
      uint2 o; o.x = fpack(ov[0],ov[1]); o.y = fpack(ov[2],ov[3]);
      *(uint2*)(h + (size_t)row*128 + col0) = o;
    }
  }
}

// ---------------- fused heads: out[:,0:3]=disp*ratio, out[:,3]=stress*ratio --------
__global__ __launch_bounds__(256) void k_heads(
  const bf16* __restrict__ h,
  const float* __restrict__ dW1, const float* __restrict__ db1,
  const float* __restrict__ dW2, const float* __restrict__ db2,
  const float* __restrict__ dW3, const float* __restrict__ db3,
  const float* __restrict__ sW1, const float* __restrict__ sb1,
  const float* __restrict__ sW2, const float* __restrict__ sb2,
  const float* __restrict__ sW3, const float* __restrict__ sb3,
  const float* __restrict__ ratio_p, float* __restrict__ out, int N)
{
  __shared__ float T1[64][132];   // +4 pad for K-major read phase
  __shared__ float T2[64][68];
  __shared__ float As[64][16];
  __shared__ float Bs[16][128];
  const float ratio = *ratio_p;
  int tid = threadIdx.x;
  int tx = tid & 31, ty = tid >> 5;
  int rowBase = blockIdx.x * 64;
  int ar = tid >> 2, akq = (tid & 3)*4;
  int bk = tid >> 4, bc = (tid & 15)*8;
  int ty2 = tid >> 4, tx2 = tid & 15;

  for(int head=0; head<2; head++){
    const float* W1h = head? sW1 : dW1;
    const float* b1h = head? sb1 : db1;
    const float* W2h = head? sW2 : dW2;
    const float* b2h = head? sb2 : db2;
    const float* W3h = head? sW3 : dW3;
    const float* b3h = head? sb3 : db3;

    // stage 1: T1 = relu(h @ W1h + b1h)   [64][128], K=128
    float acc[8][4] = {};
    for(int kt=0; kt<8; ++kt){
      int k0 = kt*16 + akq;
      int arow = rowBase + ar;
      float4 av = make_float4(0.f,0.f,0.f,0.f);
      if(arow < N){
        uint2 raw = *(const uint2*)(h + (size_t)arow*128 + k0);
        float2 f0=bfpair(raw.x), f1=bfpair(raw.y);
        av = make_float4(f0.x,f0.y,f1.x,f1.y);
      }
      *(float4*)&As[ar][akq] = av;
      int k = kt*16 + bk;
      float4 w0 = *(const float4*)(W1h + (size_t)k*128 + bc);
      float4 w1 = *(const float4*)(W1h + (size_t)k*128 + bc + 4);
      *(float4*)&Bs[bk][bc]   = w0;
      *(float4*)&Bs[bk][bc+4] = w1;
      __syncthreads();
      #pragma unroll
      for(int kk=0;kk<16;kk++){
        float4 b4 = *(float4*)&Bs[kk][tx*4];
        #pragma unroll
        for(int r=0;r<8;r++){
          float a = As[ty*8+r][kk];
          acc[r][0]+=a*b4.x; acc[r][1]+=a*b4.y; acc[r][2]+=a*b4.z; acc[r][3]+=a*b4.w;
        }
      }
      __syncthreads();
    }
    float b1v[4];
    #pragma unroll
    for(int c=0;c<4;c++) b1v[c] = b1h[tx*4+c];
    #pragma unroll
    for(int r=0;r<8;r++)
      #pragma unroll
      for(int c=0;c<4;c++)
        T1[ty*8+r][tx*4+c] = fmaxf(acc[r][c] + b1v[c], 0.f);
    __syncthreads();

    // stage 2: T2 = relu(T1 @ W2h + b2h)  [64][64], K=128
    float acc2[4][4] = {};
    for(int k=0;k<128;k++){
      float4 g4 = *(const float4*)(W2h + (size_t)k*64 + tx2*4);
      #pragma unroll
      for(int j=0;j<4;j++){
        float a = T1[ty2*4+j][k];
        acc2[j][0]+=a*g4.x; acc2[j][1]+=a*g4.y; acc2[j][2]+=a*g4.z; acc2[j][3]+=a*g4.w;
      }
    }
    float b2v[4];
    #pragma unroll
    for(int c=0;c<4;c++) b2v[c] = b2h[tx2*4+c];
    #pragma unroll
    for(int j=0;j<4;j++)
      #pragma unroll
      for(int c=0;c<4;c++)
        T2[ty2*4+j][tx2*4+c] = fmaxf(acc2[j][c]+b2v[c], 0.f);
    __syncthreads();

    // stage 3: tiny final matmul + scale + store
    if(head==0){
      if(tid < 192){
        int n = tid/3, c = tid - n*3;
        float s = b3h[c];
        for(int k=0;k<64;k++) s += T2[n][k]*W3h[k*3+c];
        int row = rowBase + n;
        if(row < N) out[(size_t)row*4 + c] = s*ratio;
      }
    } else {
      if(tid < 64){
        int n = tid;
        float s = b3h[0];
        for(int k=0;k<64;k++) s += T2[n][k]*W3h[k];
        int row = rowBase + n;
        if(row < N) out[(size_t)row*4 + 3] = s*ratio;
      }
    }
    __syncthreads();
  }
}

extern "C" void kernel_launch(void* const* d_in, const int* in_sizes, int n_in,
                              void* d_out, int out_size, void* d_ws, size_t ws_size,
                              hipStream_t stream)
{
  const float* x   = (const float*)d_in[0];
  const int*  eidx = (const int*) d_in[1];
  const float* eW1 = (const float*)d_in[2];
  const float* eb1 = (const float*)d_in[3];
  const float* eW2 = (const float*)d_in[4];
  const float* eb2 = (const float*)d_in[5];
  const float* llW = (const float*)d_in[6];
  const float* llb = (const float*)d_in[7];
  const float* lrW = (const float*)d_in[8];
  const float* lng = (const float*)d_in[9];
  const float* lnb = (const float*)d_in[10];
  const float* dW1 = (const float*)d_in[11];
  const float* db1 = (const float*)d_in[12];
  const float* dW2 = (const float*)d_in[13];
  const float* db2 = (const float*)d_in[14];
  const float* dW3 = (const float*)d_in[15];
  const float* db3 = (const float*)d_in[16];
  const float* sW1 = (const float*)d_in[17];
  const float* sb1 = (const float*)d_in[18];
  const float* sW2 = (const float*)d_in[19];
  const float* sb2 = (const float*)d_in[20];
  const float* sW3 = (const float*)d_in[21];
  const float* sb3 = (const float*)d_in[22];
  float* out = (float*)d_out;

  const int N = in_sizes[0] / 12;
  const int E = in_sizes[1] / 2;
  (void)n_in; (void)out_size; (void)ws_size;

  // workspace layout (256B aligned slots) — total ~29 MB
  char* base = (char*)d_ws;
  size_t off = 0;
  auto alloc = [&](size_t nbytes)->char*{
    char* p = base + off; off += (nbytes + 255) & ~(size_t)255; return p;
  };
  unsigned* ratio = (unsigned*)alloc(4);
  int*   deg    = (int*)  alloc((size_t)N*4);
  int*   offs   = (int*)  alloc(((size_t)N+1)*4);
  int*   pos    = (int*)  alloc((size_t)N*4);
  int*   bsum   = (int*)  alloc(256*4);
  int*   csr    = (int*)  alloc((size_t)E*4);
  float* invdeg = (float*)alloc((size_t)N*4);
  bf16*  hA     = (bf16*) alloc((size_t)N*128*2);
  bf16*  agg    = (bf16*) alloc((size_t)N*128*2);

  size_t zbytes = (size_t)((char*)offs - base);   // zero ratio + deg
  hipMemsetAsync(d_ws, 0, zbytes, stream);

  int nbE    = (E + 255)/256;
  int nbScan = (N + 1023)/1024;
  int nbTile = (N + 63)/64;
  int nbAgg  = (N + 7)/8;

  k_ratio <<<256, 256, 0, stream>>>(x, ratio, N);
  k_degree<<<nbE, 256, 0, stream>>>(eidx, deg, E, N);
  k_scan1 <<<nbScan, 256, 0, stream>>>(deg, bsum, N);
  k_scan2 <<<1, 64, 0, stream>>>(bsum, nbScan);
  k_scan3 <<<nbScan, 256, 0, stream>>>(deg, bsum, offs, pos, invdeg, N, E);
  k_bucket<<<nbE, 256, 0, stream>>>(eidx, pos, csr, E, N);

  k_encoder<<<nbTile, 256, 0, stream>>>(x, eW1, eb1, eW2, eb2, hA, N);
  for(int l=0;l<4;l++){
    k_aggregate<<<nbAgg, 256, 0, stream>>>(hA, agg, offs, csr, invdeg, N, E);
    k_sage<<<nbTile, 256, 0, stream>>>(hA, agg,
        llW + (size_t)l*128*128, llb + (size_t)l*128,
        lrW + (size_t)l*128*128, lng + (size_t)l*128, lnb + (size_t)l*128, N);
  }
  k_heads<<<nbTile, 256, 0, stream>>>(hA, dW1, db1, dW2, db2, dW3, db3,
      sW1, sb1, sW2, sb2, sW3, sb3, (const float*)ratio, out, N);
}

// Round 5
// 573.157 us; speedup vs baseline: 2.3381x; 1.1900x over previous
//
#include <hip/hip_runtime.h>
#include <hip/hip_bf16.h>

typedef __hip_bfloat16 bf16;
typedef short bf16x8 __attribute__((ext_vector_type(8)));
typedef float f32x4 __attribute__((ext_vector_type(4)));

__device__ __forceinline__ float2 bfpair(unsigned u){
  float2 r; r.x = __uint_as_float(u<<16); r.y = __uint_as_float(u & 0xffff0000u); return r;
}
__device__ __forceinline__ float bfu(unsigned short u){ return __uint_as_float(((unsigned)u)<<16); }
__device__ __forceinline__ unsigned f2bf(float f){
  unsigned u = __float_as_uint(f);
  return (u + 0x7fffu + ((u>>16)&1u)) >> 16;
}
__device__ __forceinline__ unsigned fpack(float a, float b){
  return (f2bf(b)<<16) | f2bf(a);
}
__device__ __forceinline__ int edge_is64(const int* e){
  return (e[1]==0) & (e[3]==0) & (e[5]==0);
}
__device__ __forceinline__ int edge_ld(const int* e, int is64, int idx){
  return e[is64 ? 2*idx : idx];
}

// ---------------- ratio = max ||x[:,3:6]|| ----------------
__global__ void k_ratio(const float* __restrict__ x, unsigned* __restrict__ ratio, int N){
  int i = blockIdx.x*blockDim.x + threadIdx.x;
  int stride = gridDim.x*blockDim.x;
  float m = 0.f;
  for(; i<N; i+=stride){
    float a = x[(size_t)i*12+3];
    float b = x[(size_t)i*12+4];
    float c = x[(size_t)i*12+5];
    m = fmaxf(m, sqrtf(a*a+b*b+c*c));
  }
  #pragma unroll
  for(int off=1; off<64; off<<=1) m = fmaxf(m, __shfl_xor(m, off));
  if((threadIdx.x & 63)==0) atomicMax(ratio, __float_as_uint(m));
}

// ---------------- degree histogram ----------------
__global__ void k_degree(const int* __restrict__ eidx, int* __restrict__ deg, int E, int N){
  int e = blockIdx.x*blockDim.x + threadIdx.x;
  if(e>=E) return;
  int is64 = edge_is64(eidx);
  int d = edge_ld(eidx, is64, E+e);
  if((unsigned)d < (unsigned)N) atomicAdd(&deg[d], 1);
}

// ---------------- 3-kernel exclusive scan over deg[N] ----------------
__global__ void k_scan1(const int* __restrict__ deg, int* __restrict__ bsum, int N){
  int t = threadIdx.x;
  int idx0 = blockIdx.x*1024 + t*4;
  int s=0;
  #pragma unroll
  for(int i=0;i<4;i++){ int idx=idx0+i; if(idx<N) s += deg[idx]; }
  #pragma unroll
  for(int off=1; off<64; off<<=1) s += __shfl_xor(s, off);
  __shared__ int ws4[4];
  if((t&63)==0) ws4[t>>6]=s;
  __syncthreads();
  if(t==0) bsum[blockIdx.x]=ws4[0]+ws4[1]+ws4[2]+ws4[3];
}
__global__ void k_scan2(int* bsum, int nb){
  if(threadIdx.x==0 && blockIdx.x==0){
    int acc=0;
    for(int i=0;i<nb;i++){ int v=bsum[i]; bsum[i]=acc; acc+=v; }
  }
}
__global__ void k_scan3(const int* __restrict__ deg, const int* __restrict__ bsum,
                        int* __restrict__ offs, int* __restrict__ pos,
                        float* __restrict__ invdeg, int N, int E){
  int t = threadIdx.x;
  int idx0 = blockIdx.x*1024 + t*4;
  int d[4]; int s=0;
  #pragma unroll
  for(int i=0;i<4;i++){ int idx=idx0+i; d[i] = (idx<N)? deg[idx]:0; s+=d[i]; }
  int lane=t&63, w=t>>6;
  int incl=s;
  #pragma unroll
  for(int off=1; off<64; off<<=1){ int v=__shfl_up(incl, (unsigned)off); if(lane>=off) incl+=v; }
  __shared__ int wsum[4];
  if(lane==63) wsum[w]=incl;
  __syncthreads();
  int base = bsum[blockIdx.x];
  for(int i=0;i<w;i++) base += wsum[i];
  int run = base + incl - s;
  #pragma unroll
  for(int i=0;i<4;i++){
    int idx=idx0+i;
    if(idx<N){
      offs[idx]=run; pos[idx]=run;
      invdeg[idx] = 1.0f / (float)(d[i]>0? d[i]:1);
    }
    run += d[i];
  }
  if(blockIdx.x==0 && t==0) offs[N]=E;
}

// ---------------- bucket edges into CSR ----------------
__global__ void k_bucket(const int* __restrict__ eidx, int* __restrict__ pos,
                         int* __restrict__ csr, int E, int N){
  int e = blockIdx.x*blockDim.x + threadIdx.x;
  if(e>=E) return;
  int is64 = edge_is64(eidx);
  int d = edge_ld(eidx, is64, E+e);
  int s = edge_ld(eidx, is64, e);
  if((unsigned)d >= (unsigned)N) return;
  if((unsigned)s >= (unsigned)N) s = 0;
  int p = atomicAdd(&pos[d], 1);
  if((unsigned)p < (unsigned)E) csr[p] = s;
}

// ---------------- weight transpose+convert: WT[l][n][k] = bf16(cat(Wl;Wr)[k][n]) ----
__global__ void k_wconv(const float* __restrict__ llW, const float* __restrict__ lrW,
                        unsigned short* __restrict__ WT){
  int idx = blockIdx.x*256 + threadIdx.x;   // 4*128*256 = 131072
  int l = idx >> 15;
  int rem = idx & 32767;
  int n = rem >> 8;
  int k = rem & 255;
  float v = (k < 128) ? llW[(size_t)l*16384 + (size_t)k*128 + n]
                      : lrW[(size_t)l*16384 + (size_t)(k-128)*128 + n];
  WT[idx] = (unsigned short)f2bf(v);
}

// ---------------- mean aggregation: half-wave (32 lanes) per dst row ----------------
__global__ __launch_bounds__(256) void k_aggregate(
    const bf16* __restrict__ h, bf16* __restrict__ agg,
    const int* __restrict__ offs, const int* __restrict__ csr,
    const float* __restrict__ invdeg, int N, int E){
  int row = blockIdx.x*8 + (threadIdx.x>>5);
  int l = threadIdx.x & 31;
  if(row >= N) return;
  int s = offs[row], e = offs[row+1];
  s = max(0, min(s, E)); e = max(s, min(e, E));
  float a0=0.f, a1=0.f, a2=0.f, a3=0.f;
  int i = s;
  for(; i+4<=e; i+=4){
    int j0=csr[i], j1=csr[i+1], j2=csr[i+2], j3=csr[i+3];
    uint2 u0 = *(const uint2*)(h + (size_t)j0*128 + l*4);
    uint2 u1 = *(const uint2*)(h + (size_t)j1*128 + l*4);
    uint2 u2 = *(const uint2*)(h + (size_t)j2*128 + l*4);
    uint2 u3 = *(const uint2*)(h + (size_t)j3*128 + l*4);
    float2 p0=bfpair(u0.x), q0=bfpair(u0.y);
    float2 p1=bfpair(u1.x), q1=bfpair(u1.y);
    float2 p2=bfpair(u2.x), q2=bfpair(u2.y);
    float2 p3=bfpair(u3.x), q3=bfpair(u3.y);
    a0 += p0.x+p1.x+p2.x+p3.x;
    a1 += p0.y+p1.y+p2.y+p3.y;
    a2 += q0.x+q1.x+q2.x+q3.x;
    a3 += q0.y+q1.y+q2.y+q3.y;
  }
  for(; i<e; ++i){
    int j = csr[i];
    uint2 u = *(const uint2*)(h + (size_t)j*128 + l*4);
    float2 p=bfpair(u.x), q=bfpair(u.y);
    a0+=p.x; a1+=p.y; a2+=q.x; a3+=q.y;
  }
  float id = invdeg[row];
  uint2 o; o.x = fpack(a0*id, a1*id); o.y = fpack(a2*id, a3*id);
  *(uint2*)(agg + (size_t)row*128 + l*4) = o;
}

// ---------------- encoder: h = relu(x@W1+b1)@W2+b2 -> bf16 ----------------
__global__ __launch_bounds__(256) void k_encoder(
  const float* __restrict__ x,
  const float* __restrict__ W1, const float* __restrict__ b1,
  const float* __restrict__ W2, const float* __restrict__ b2,
  bf16* __restrict__ h, int N)
{
  __shared__ float Xs[64][12];
  __shared__ float W1s[12][128];
  __shared__ float T1[64][128];
  __shared__ float Bs[16][128];
  __shared__ float b1s[128];
  int tid = threadIdx.x;
  int tx = tid & 31, ty = tid >> 5;
  int rowBase = blockIdx.x*64;
  for(int idx=tid; idx<768; idx+=256){
    int r = idx/12, c = idx - r*12;
    int row = rowBase + r;
    Xs[r][c] = (row<N)? x[(size_t)row*12+c] : 0.f;
  }
  for(int idx=tid; idx<1536; idx+=256) W1s[idx>>7][idx&127] = W1[idx];
  if(tid<128) b1s[tid] = b1[tid];
  __syncthreads();
  float acc[8][4] = {};
  #pragma unroll
  for(int k=0;k<12;k++){
    float4 w4 = *(float4*)&W1s[k][tx*4];
    #pragma unroll
    for(int r=0;r<8;r++){
      float a = Xs[ty*8+r][k];
      acc[r][0]+=a*w4.x; acc[r][1]+=a*w4.y; acc[r][2]+=a*w4.z; acc[r][3]+=a*w4.w;
    }
  }
  #pragma unroll
  for(int r=0;r<8;r++)
    #pragma unroll
    for(int c=0;c<4;c++)
      T1[ty*8+r][tx*4+c] = fmaxf(acc[r][c] + b1s[tx*4+c], 0.f);
  __syncthreads();
  float acc2[8][4] = {};
  int bk = tid>>4, bc = (tid&15)*8;
  for(int kt=0;kt<8;kt++){
    int k = kt*16 + bk;
    float4 w0 = *(const float4*)(W2 + (size_t)k*128 + bc);
    float4 w1 = *(const float4*)(W2 + (size_t)k*128 + bc + 4);
    *(float4*)&Bs[bk][bc]   = w0;
    *(float4*)&Bs[bk][bc+4] = w1;
    __syncthreads();
    #pragma unroll
    for(int kk=0;kk<16;kk++){
      float4 b4 = *(float4*)&Bs[kk][tx*4];
      #pragma unroll
      for(int r=0;r<8;r++){
        float a = T1[ty*8+r][kt*16+kk];
        acc2[r][0]+=a*b4.x; acc2[r][1]+=a*b4.y; acc2[r][2]+=a*b4.z; acc2[r][3]+=a*b4.w;
      }
    }
    __syncthreads();
  }
  #pragma unroll
  for(int r=0;r<8;r++){
    int row = rowBase + ty*8 + r;
    if(row<N){
      float o0 = acc2[r][0] + b2[tx*4+0];
      float o1 = acc2[r][1] + b2[tx*4+1];
      float o2 = acc2[r][2] + b2[tx*4+2];
      float o3 = acc2[r][3] + b2[tx*4+3];
      uint2 o; o.x = fpack(o0,o1); o.y = fpack(o2,o3);
      *(uint2*)(h + (size_t)row*128 + tx*4) = o;
    }
  }
}

// ---------------- SAGE layer via MFMA: y=[agg|h]@Wcat + bl; LN; h += relu(y) -------
// Wave w owns rows [rowBase+16w, rowBase+16w+16): A-frags and all stores stay in-tile.
// A: lane holds A[m=lane&15][k=quad*8+j] (16B global load from agg/h row).
// B: lane holds B[k=quad*8+j][n=lane&15] = WT[n][k] (16B global load, L2-resident).
// C/D: row=quad*4+reg, col=lane&15  -> LN reduces over 16 lanes of the quad.
__global__ __launch_bounds__(256) void k_sage_mfma(
    bf16* __restrict__ h, const bf16* __restrict__ agg,
    const unsigned short* __restrict__ WT,   // [128 n][256 k] bf16 bits
    const float* __restrict__ bl, const float* __restrict__ lng,
    const float* __restrict__ lnb, int N)
{
  int tid = threadIdx.x;
  int lane = tid & 63;
  int w = tid >> 6;              // m-tile 0..3
  int q = lane >> 4;             // quad 0..3
  int p = lane & 15;
  int rowBase = blockIdx.x*64;

  int am = rowBase + w*16 + p;   // A-operand row for this lane
  bool arow_ok = am < N;
  const unsigned short* aggRow = (const unsigned short*)agg + (size_t)am*128;
  const unsigned short* hRow   = (const unsigned short*)h   + (size_t)am*128;

  f32x4 acc[8];
  #pragma unroll
  for(int nt=0; nt<8; nt++) acc[nt] = (f32x4){0.f,0.f,0.f,0.f};

  #pragma unroll
  for(int ks=0; ks<8; ks++){
    int koff = ks*32 + q*8;      // k in [0,256)
    bf16x8 afrag = {0,0,0,0,0,0,0,0};
    if(arow_ok){
      const unsigned short* src = (koff < 128) ? (aggRow + koff) : (hRow + (koff-128));
      afrag = *(const bf16x8*)src;
    }
    #pragma unroll
    for(int nt=0; nt<8; nt++){
      const unsigned short* bsrc = WT + (size_t)(nt*16 + p)*256 + koff;
      bf16x8 bfrag = *(const bf16x8*)bsrc;
      acc[nt] = __builtin_amdgcn_mfma_f32_16x16x32_bf16(afrag, bfrag, acc[nt], 0, 0, 0);
    }
  }

  // epilogue: bias + LayerNorm + residual ReLU, in place
  float blv[8], gvv[8], bvv[8];
  #pragma unroll
  for(int nt=0; nt<8; nt++){
    int col = nt*16 + p;
    blv[nt] = bl[col]; gvv[nt] = lng[col]; bvv[nt] = lnb[col];
  }
  unsigned short* hu = (unsigned short*)h;
  #pragma unroll
  for(int r=0; r<4; r++){
    int row = rowBase + w*16 + q*4 + r;
    float y[8]; float s = 0.f, sq = 0.f;
    #pragma unroll
    for(int nt=0; nt<8; nt++){
      float v = acc[nt][r] + blv[nt];
      y[nt] = v; s += v; sq += v*v;
    }
    #pragma unroll
    for(int off=1; off<16; off<<=1){ s += __shfl_xor(s, off); sq += __shfl_xor(sq, off); }
    float mu = s*(1.f/128.f);
    float var = fmaxf(sq*(1.f/128.f) - mu*mu, 0.f);
    float rstd = rsqrtf(var + 1e-5f);
    if(row < N){
      #pragma unroll
      for(int nt=0; nt<8; nt++){
        int col = nt*16 + p;
        float hv = bfu(hu[(size_t)row*128 + col]);
        float o = hv + fmaxf((y[nt]-mu)*rstd*gvv[nt] + bvv[nt], 0.f);
        hu[(size_t)row*128 + col] = (unsigned short)f2bf(o);
      }
    }
  }
}

// ---------------- heads: blockIdx.y = head (0 disp, 1 stress) ---------------------
__global__ __launch_bounds__(256) void k_heads(
  const bf16* __restrict__ h,
  const float* __restrict__ dW1, const float* __restrict__ db1,
  const float* __restrict__ dW2, const float* __restrict__ db2,
  const float* __restrict__ dW3, const float* __restrict__ db3,
  const float* __restrict__ sW1, const float* __restrict__ sb1,
  const float* __restrict__ sW2, const float* __restrict__ sb2,
  const float* __restrict__ sW3, const float* __restrict__ sb3,
  const float* __restrict__ ratio_p, float* __restrict__ out, int N)
{
  __shared__ unsigned short T1[64][130];   // bf16 bits; odd-ish stride kills conflicts
  __shared__ unsigned short T2[64][66];
  __shared__ float As[64][16];
  __shared__ float Bs[16][128];
  const float ratio = *ratio_p;
  int head = blockIdx.y;
  int tid = threadIdx.x;
  int tx = tid & 31, ty = tid >> 5;
  int rowBase = blockIdx.x * 64;
  int ar = tid >> 2, akq = (tid & 3)*4;
  int bk = tid >> 4, bc = (tid & 15)*8;
  int ty2 = tid >> 4, tx2 = tid & 15;

  const float* W1h = head? sW1 : dW1;
  const float* b1h = head? sb1 : db1;
  const float* W2h = head? sW2 : dW2;
  const float* b2h = head? sb2 : db2;
  const float* W3h = head? sW3 : dW3;
  const float* b3h = head? sb3 : db3;

  // stage 1: T1 = relu(h @ W1h + b1h)   [64][128], K=128
  float acc[8][4] = {};
  for(int kt=0; kt<8; ++kt){
    int k0 = kt*16 + akq;
    int arow = rowBase + ar;
    float4 av = make_float4(0.f,0.f,0.f,0.f);
    if(arow < N){
      uint2 raw = *(const uint2*)(h + (size_t)arow*128 + k0);
      float2 f0=bfpair(raw.x), f1=bfpair(raw.y);
      av = make_float4(f0.x,f0.y,f1.x,f1.y);
    }
    *(float4*)&As[ar][akq] = av;
    int k = kt*16 + bk;
    float4 w0 = *(const float4*)(W1h + (size_t)k*128 + bc);
    float4 w1 = *(const float4*)(W1h + (size_t)k*128 + bc + 4);
    *(float4*)&Bs[bk][bc]   = w0;
    *(float4*)&Bs[bk][bc+4] = w1;
    __syncthreads();
    #pragma unroll
    for(int kk=0;kk<16;kk++){
      float4 b4 = *(float4*)&Bs[kk][tx*4];
      #pragma unroll
      for(int r=0;r<8;r++){
        float a = As[ty*8+r][kk];
        acc[r][0]+=a*b4.x; acc[r][1]+=a*b4.y; acc[r][2]+=a*b4.z; acc[r][3]+=a*b4.w;
      }
    }
    __syncthreads();
  }
  float b1v[4];
  #pragma unroll
  for(int c=0;c<4;c++) b1v[c] = b1h[tx*4+c];
  #pragma unroll
  for(int r=0;r<8;r++)
    #pragma unroll
    for(int c=0;c<4;c++)
      T1[ty*8+r][tx*4+c] = (unsigned short)f2bf(fmaxf(acc[r][c] + b1v[c], 0.f));
  __syncthreads();

  // stage 2: T2 = relu(T1 @ W2h + b2h)  [64][64], K=128
  float acc2[4][4] = {};
  for(int k=0;k<128;k++){
    float4 g4 = *(const float4*)(W2h + (size_t)k*64 + tx2*4);
    #pragma unroll
    for(int j=0;j<4;j++){
      float a = bfu(T1[ty2*4+j][k]);
      acc2[j][0]+=a*g4.x; acc2[j][1]+=a*g4.y; acc2[j][2]+=a*g4.z; acc2[j][3]+=a*g4.w;
    }
  }
  float b2v[4];
  #pragma unroll
  for(int c=0;c<4;c++) b2v[c] = b2h[tx2*4+c];
  #pragma unroll
  for(int j=0;j<4;j++)
    #pragma unroll
    for(int c=0;c<4;c++)
      T2[ty2*4+j][tx2*4+c] = (unsigned short)f2bf(fmaxf(acc2[j][c]+b2v[c], 0.f));
  __syncthreads();

  // stage 3: tiny final matmul + scale + store
  if(head==0){
    if(tid < 192){
      int n = tid/3, c = tid - n*3;
      float s = b3h[c];
      for(int k=0;k<64;k++) s += bfu(T2[n][k])*W3h[k*3+c];
      int row = rowBase + n;
      if(row < N) out[(size_t)row*4 + c] = s*ratio;
    }
  } else {
    if(tid < 64){
      int n = tid;
      float s = b3h[0];
      for(int k=0;k<64;k++) s += bfu(T2[n][k])*W3h[k];
      int row = rowBase + n;
      if(row < N) out[(size_t)row*4 + 3] = s*ratio;
    }
  }
}

extern "C" void kernel_launch(void* const* d_in, const int* in_sizes, int n_in,
                              void* d_out, int out_size, void* d_ws, size_t ws_size,
                              hipStream_t stream)
{
  const float* x   = (const float*)d_in[0];
  const int*  eidx = (const int*) d_in[1];
  const float* eW1 = (const float*)d_in[2];
  const float* eb1 = (const float*)d_in[3];
  const float* eW2 = (const float*)d_in[4];
  const float* eb2 = (const float*)d_in[5];
  const float* llW = (const float*)d_in[6];
  const float* llb = (const float*)d_in[7];
  const float* lrW = (const float*)d_in[8];
  const float* lng = (const float*)d_in[9];
  const float* lnb = (const float*)d_in[10];
  const float* dW1 = (const float*)d_in[11];
  const float* db1 = (const float*)d_in[12];
  const float* dW2 = (const float*)d_in[13];
  const float* db2 = (const float*)d_in[14];
  const float* dW3 = (const float*)d_in[15];
  const float* db3 = (const float*)d_in[16];
  const float* sW1 = (const float*)d_in[17];
  const float* sb1 = (const float*)d_in[18];
  const float* sW2 = (const float*)d_in[19];
  const float* sb2 = (const float*)d_in[20];
  const float* sW3 = (const float*)d_in[21];
  const float* sb3 = (const float*)d_in[22];
  float* out = (float*)d_out;

  const int N = in_sizes[0] / 12;
  const int E = in_sizes[1] / 2;
  (void)n_in; (void)out_size; (void)ws_size;

  // workspace layout (256B aligned slots) — ~29.5 MB
  char* base = (char*)d_ws;
  size_t off = 0;
  auto alloc = [&](size_t nbytes)->char*{
    char* p = base + off; off += (nbytes + 255) & ~(size_t)255; return p;
  };
  unsigned* ratio = (unsigned*)alloc(4);
  int*   deg    = (int*)  alloc((size_t)N*4);
  int*   offs   = (int*)  alloc(((size_t)N+1)*4);
  int*   pos    = (int*)  alloc((size_t)N*4);
  int*   bsum   = (int*)  alloc(256*4);
  int*   csr    = (int*)  alloc((size_t)E*4);
  float* invdeg = (float*)alloc((size_t)N*4);
  bf16*  hA     = (bf16*) alloc((size_t)N*128*2);
  bf16*  agg    = (bf16*) alloc((size_t)N*128*2);
  unsigned short* WTs = (unsigned short*)alloc((size_t)4*128*256*2);  // sage W^T bf16

  size_t zbytes = (size_t)((char*)offs - base);   // zero ratio + deg
  hipMemsetAsync(d_ws, 0, zbytes, stream);

  int nbE    = (E + 255)/256;
  int nbScan = (N + 1023)/1024;
  int nbTile = (N + 63)/64;
  int nbAgg  = (N + 7)/8;

  k_ratio <<<256, 256, 0, stream>>>(x, ratio, N);
  k_degree<<<nbE, 256, 0, stream>>>(eidx, deg, E, N);
  k_scan1 <<<nbScan, 256, 0, stream>>>(deg, bsum, N);
  k_scan2 <<<1, 64, 0, stream>>>(bsum, nbScan);
  k_scan3 <<<nbScan, 256, 0, stream>>>(deg, bsum, offs, pos, invdeg, N, E);
  k_bucket<<<nbE, 256, 0, stream>>>(eidx, pos, csr, E, N);
  k_wconv <<<512, 256, 0, stream>>>(llW, lrW, WTs);

  k_encoder<<<nbTile, 256, 0, stream>>>(x, eW1, eb1, eW2, eb2, hA, N);
  for(int l=0;l<4;l++){
    k_aggregate<<<nbAgg, 256, 0, stream>>>(hA, agg, offs, csr, invdeg, N, E);
    k_sage_mfma<<<nbTile, 256, 0, stream>>>(hA, agg,
        WTs + (size_t)l*128*256,
        llb + (size_t)l*128, lng + (size_t)l*128, lnb + (size_t)l*128, N);
  }
  dim3 hgrid(nbTile, 2);
  k_heads<<<hgrid, 256, 0, stream>>>(hA, dW1, db1, dW2, db2, dW3, db3,
      sW1, sb1, sW2, sb2, sW3, sb3, (const float*)ratio, out, N);
}

// Round 6
// 552.899 us; speedup vs baseline: 2.4237x; 1.0366x over previous
//
#include <hip/hip_runtime.h>
#include <hip/hip_bf16.h>

typedef __hip_bfloat16 bf16;
typedef short bf16x8 __attribute__((ext_vector_type(8)));
typedef float f32x4 __attribute__((ext_vector_type(4)));

__device__ __forceinline__ float2 bfpair(unsigned u){
  float2 r; r.x = __uint_as_float(u<<16); r.y = __uint_as_float(u & 0xffff0000u); return r;
}
__device__ __forceinline__ float bfu(unsigned short u){ return __uint_as_float(((unsigned)u)<<16); }
__device__ __forceinline__ unsigned f2bf(float f){
  unsigned u = __float_as_uint(f);
  return (u + 0x7fffu + ((u>>16)&1u)) >> 16;
}
__device__ __forceinline__ unsigned fpack(float a, float b){
  return (f2bf(b)<<16) | f2bf(a);
}
__device__ __forceinline__ int edge_is64(const int* e){
  return (e[1]==0) & (e[3]==0) & (e[5]==0);
}
__device__ __forceinline__ int edge_ld(const int* e, int is64, int idx){
  return e[is64 ? 2*idx : idx];
}

// ---------------- ratio = max ||x[:,3:6]|| ----------------
__global__ void k_ratio(const float* __restrict__ x, unsigned* __restrict__ ratio, int N){
  int i = blockIdx.x*blockDim.x + threadIdx.x;
  int stride = gridDim.x*blockDim.x;
  float m = 0.f;
  for(; i<N; i+=stride){
    float a = x[(size_t)i*12+3];
    float b = x[(size_t)i*12+4];
    float c = x[(size_t)i*12+5];
    m = fmaxf(m, sqrtf(a*a+b*b+c*c));
  }
  #pragma unroll
  for(int off=1; off<64; off<<=1) m = fmaxf(m, __shfl_xor(m, off));
  if((threadIdx.x & 63)==0) atomicMax(ratio, __float_as_uint(m));
}

// ---------------- degree histogram ----------------
__global__ void k_degree(const int* __restrict__ eidx, int* __restrict__ deg, int E, int N){
  int e = blockIdx.x*blockDim.x + threadIdx.x;
  if(e>=E) return;
  int is64 = edge_is64(eidx);
  int d = edge_ld(eidx, is64, E+e);
  if((unsigned)d < (unsigned)N) atomicAdd(&deg[d], 1);
}

// ---------------- 3-kernel exclusive scan over deg[N] ----------------
__global__ void k_scan1(const int* __restrict__ deg, int* __restrict__ bsum, int N){
  int t = threadIdx.x;
  int idx0 = blockIdx.x*1024 + t*4;
  int s=0;
  #pragma unroll
  for(int i=0;i<4;i++){ int idx=idx0+i; if(idx<N) s += deg[idx]; }
  #pragma unroll
  for(int off=1; off<64; off<<=1) s += __shfl_xor(s, off);
  __shared__ int ws4[4];
  if((t&63)==0) ws4[t>>6]=s;
  __syncthreads();
  if(t==0) bsum[blockIdx.x]=ws4[0]+ws4[1]+ws4[2]+ws4[3];
}
__global__ void k_scan2(int* bsum, int nb){
  if(threadIdx.x==0 && blockIdx.x==0){
    int acc=0;
    for(int i=0;i<nb;i++){ int v=bsum[i]; bsum[i]=acc; acc+=v; }
  }
}
__global__ void k_scan3(const int* __restrict__ deg, const int* __restrict__ bsum,
                        int* __restrict__ offs, int* __restrict__ pos,
                        float* __restrict__ invdeg, int N, int E){
  int t = threadIdx.x;
  int idx0 = blockIdx.x*1024 + t*4;
  int d[4]; int s=0;
  #pragma unroll
  for(int i=0;i<4;i++){ int idx=idx0+i; d[i] = (idx<N)? deg[idx]:0; s+=d[i]; }
  int lane=t&63, w=t>>6;
  int incl=s;
  #pragma unroll
  for(int off=1; off<64; off<<=1){ int v=__shfl_up(incl, (unsigned)off); if(lane>=off) incl+=v; }
  __shared__ int wsum[4];
  if(lane==63) wsum[w]=incl;
  __syncthreads();
  int base = bsum[blockIdx.x];
  for(int i=0;i<w;i++) base += wsum[i];
  int run = base + incl - s;
  #pragma unroll
  for(int i=0;i<4;i++){
    int idx=idx0+i;
    if(idx<N){
      offs[idx]=run; pos[idx]=run;
      invdeg[idx] = 1.0f / (float)(d[i]>0? d[i]:1);
    }
    run += d[i];
  }
  if(blockIdx.x==0 && t==0) offs[N]=E;
}

// ---------------- bucket edges into CSR ----------------
__global__ void k_bucket(const int* __restrict__ eidx, int* __restrict__ pos,
                         int* __restrict__ csr, int E, int N){
  int e = blockIdx.x*blockDim.x + threadIdx.x;
  if(e>=E) return;
  int is64 = edge_is64(eidx);
  int d = edge_ld(eidx, is64, E+e);
  int s = edge_ld(eidx, is64, e);
  if((unsigned)d >= (unsigned)N) return;
  if((unsigned)s >= (unsigned)N) s = 0;
  int p = atomicAdd(&pos[d], 1);
  if((unsigned)p < (unsigned)E) csr[p] = s;
}

// ---------------- weight transpose+convert: sage WT[l][n][k] ----------------
__global__ void k_wconv(const float* __restrict__ llW, const float* __restrict__ lrW,
                        unsigned short* __restrict__ WT){
  int idx = blockIdx.x*256 + threadIdx.x;   // 4*128*256 = 131072
  int l = idx >> 15;
  int rem = idx & 32767;
  int n = rem >> 8;
  int k = rem & 255;
  float v = (k < 128) ? llW[(size_t)l*16384 + (size_t)k*128 + n]
                      : lrW[(size_t)l*16384 + (size_t)(k-128)*128 + n];
  WT[idx] = (unsigned short)f2bf(v);
}

// ---------------- head weight transpose+convert ----------------
// WT1[256 n][128 k]: n<128 disp W1, else stress W1. WT2[128 n][128 k]: n<64 dW2, else sW2.
__global__ void k_wconv_heads(const float* __restrict__ dW1, const float* __restrict__ sW1,
                              const float* __restrict__ dW2, const float* __restrict__ sW2,
                              unsigned short* __restrict__ WT1, unsigned short* __restrict__ WT2){
  int idx = blockIdx.x*256 + threadIdx.x;
  if(idx < 32768){
    int n = idx >> 7, k = idx & 127;
    float v = (n < 128) ? dW1[(size_t)k*128 + n] : sW1[(size_t)k*128 + (n-128)];
    WT1[idx] = (unsigned short)f2bf(v);
  } else if(idx < 49152){
    int j = idx - 32768;
    int n = j >> 7, k = j & 127;
    float v = (n < 64) ? dW2[(size_t)k*64 + n] : sW2[(size_t)k*64 + (n-64)];
    WT2[j] = (unsigned short)f2bf(v);
  }
}

// ---------------- mean aggregation: half-wave (32 lanes) per dst row ----------------
__global__ __launch_bounds__(256) void k_aggregate(
    const bf16* __restrict__ h, bf16* __restrict__ agg,
    const int* __restrict__ offs, const int* __restrict__ csr,
    const float* __restrict__ invdeg, int N, int E){
  int row = blockIdx.x*8 + (threadIdx.x>>5);
  int l = threadIdx.x & 31;
  if(row >= N) return;
  int s = offs[row], e = offs[row+1];
  s = max(0, min(s, E)); e = max(s, min(e, E));
  float a0=0.f, a1=0.f, a2=0.f, a3=0.f;
  int i = s;
  for(; i+4<=e; i+=4){
    int j0=csr[i], j1=csr[i+1], j2=csr[i+2], j3=csr[i+3];
    uint2 u0 = *(const uint2*)(h + (size_t)j0*128 + l*4);
    uint2 u1 = *(const uint2*)(h + (size_t)j1*128 + l*4);
    uint2 u2 = *(const uint2*)(h + (size_t)j2*128 + l*4);
    uint2 u3 = *(const uint2*)(h + (size_t)j3*128 + l*4);
    float2 p0=bfpair(u0.x), q0=bfpair(u0.y);
    float2 p1=bfpair(u1.x), q1=bfpair(u1.y);
    float2 p2=bfpair(u2.x), q2=bfpair(u2.y);
    float2 p3=bfpair(u3.x), q3=bfpair(u3.y);
    a0 += p0.x+p1.x+p2.x+p3.x;
    a1 += p0.y+p1.y+p2.y+p3.y;
    a2 += q0.x+q1.x+q2.x+q3.x;
    a3 += q0.y+q1.y+q2.y+q3.y;
  }
  for(; i<e; ++i){
    int j = csr[i];
    uint2 u = *(const uint2*)(h + (size_t)j*128 + l*4);
    float2 p=bfpair(u.x), q=bfpair(u.y);
    a0+=p.x; a1+=p.y; a2+=q.x; a3+=q.y;
  }
  float id = invdeg[row];
  uint2 o; o.x = fpack(a0*id, a1*id); o.y = fpack(a2*id, a3*id);
  *(uint2*)(agg + (size_t)row*128 + l*4) = o;
}

// ---------------- encoder: h = relu(x@W1+b1)@W2+b2 -> bf16 ----------------
__global__ __launch_bounds__(256) void k_encoder(
  const float* __restrict__ x,
  const float* __restrict__ W1, const float* __restrict__ b1,
  const float* __restrict__ W2, const float* __restrict__ b2,
  bf16* __restrict__ h, int N)
{
  __shared__ float Xs[64][12];
  __shared__ float W1s[12][128];
  __shared__ float T1[64][128];
  __shared__ float Bs[16][128];
  __shared__ float b1s[128];
  int tid = threadIdx.x;
  int tx = tid & 31, ty = tid >> 5;
  int rowBase = blockIdx.x*64;
  for(int idx=tid; idx<768; idx+=256){
    int r = idx/12, c = idx - r*12;
    int row = rowBase + r;
    Xs[r][c] = (row<N)? x[(size_t)row*12+c] : 0.f;
  }
  for(int idx=tid; idx<1536; idx+=256) W1s[idx>>7][idx&127] = W1[idx];
  if(tid<128) b1s[tid] = b1[tid];
  __syncthreads();
  float acc[8][4] = {};
  #pragma unroll
  for(int k=0;k<12;k++){
    float4 w4 = *(float4*)&W1s[k][tx*4];
    #pragma unroll
    for(int r=0;r<8;r++){
      float a = Xs[ty*8+r][k];
      acc[r][0]+=a*w4.x; acc[r][1]+=a*w4.y; acc[r][2]+=a*w4.z; acc[r][3]+=a*w4.w;
    }
  }
  #pragma unroll
  for(int r=0;r<8;r++)
    #pragma unroll
    for(int c=0;c<4;c++)
      T1[ty*8+r][tx*4+c] = fmaxf(acc[r][c] + b1s[tx*4+c], 0.f);
  __syncthreads();
  float acc2[8][4] = {};
  int bk = tid>>4, bc = (tid&15)*8;
  for(int kt=0;kt<8;kt++){
    int k = kt*16 + bk;
    float4 w0 = *(const float4*)(W2 + (size_t)k*128 + bc);
    float4 w1 = *(const float4*)(W2 + (size_t)k*128 + bc + 4);
    *(float4*)&Bs[bk][bc]   = w0;
    *(float4*)&Bs[bk][bc+4] = w1;
    __syncthreads();
    #pragma unroll
    for(int kk=0;kk<16;kk++){
      float4 b4 = *(float4*)&Bs[kk][tx*4];
      #pragma unroll
      for(int r=0;r<8;r++){
        float a = T1[ty*8+r][kt*16+kk];
        acc2[r][0]+=a*b4.x; acc2[r][1]+=a*b4.y; acc2[r][2]+=a*b4.z; acc2[r][3]+=a*b4.w;
      }
    }
    __syncthreads();
  }
  #pragma unroll
  for(int r=0;r<8;r++){
    int row = rowBase + ty*8 + r;
    if(row<N){
      float o0 = acc2[r][0] + b2[tx*4+0];
      float o1 = acc2[r][1] + b2[tx*4+1];
      float o2 = acc2[r][2] + b2[tx*4+2];
      float o3 = acc2[r][3] + b2[tx*4+3];
      uint2 o; o.x = fpack(o0,o1); o.y = fpack(o2,o3);
      *(uint2*)(h + (size_t)row*128 + tx*4) = o;
    }
  }
}

// ---------------- SAGE layer via MFMA (verified R5) ----------------
__global__ __launch_bounds__(256) void k_sage_mfma(
    bf16* __restrict__ h, const bf16* __restrict__ agg,
    const unsigned short* __restrict__ WT,   // [128 n][256 k] bf16 bits
    const float* __restrict__ bl, const float* __restrict__ lng,
    const float* __restrict__ lnb, int N)
{
  int tid = threadIdx.x;
  int lane = tid & 63;
  int w = tid >> 6;
  int q = lane >> 4;
  int p = lane & 15;
  int rowBase = blockIdx.x*64;

  int am = rowBase + w*16 + p;
  bool arow_ok = am < N;
  const unsigned short* aggRow = (const unsigned short*)agg + (size_t)am*128;
  const unsigned short* hRow   = (const unsigned short*)h   + (size_t)am*128;

  f32x4 acc[8];
  #pragma unroll
  for(int nt=0; nt<8; nt++) acc[nt] = (f32x4){0.f,0.f,0.f,0.f};

  #pragma unroll
  for(int ks=0; ks<8; ks++){
    int koff = ks*32 + q*8;
    bf16x8 afrag = {0,0,0,0,0,0,0,0};
    if(arow_ok){
      const unsigned short* src = (koff < 128) ? (aggRow + koff) : (hRow + (koff-128));
      afrag = *(const bf16x8*)src;
    }
    #pragma unroll
    for(int nt=0; nt<8; nt++){
      const unsigned short* bsrc = WT + (size_t)(nt*16 + p)*256 + koff;
      bf16x8 bfrag = *(const bf16x8*)bsrc;
      acc[nt] = __builtin_amdgcn_mfma_f32_16x16x32_bf16(afrag, bfrag, acc[nt], 0, 0, 0);
    }
  }

  float blv[8], gvv[8], bvv[8];
  #pragma unroll
  for(int nt=0; nt<8; nt++){
    int col = nt*16 + p;
    blv[nt] = bl[col]; gvv[nt] = lng[col]; bvv[nt] = lnb[col];
  }
  unsigned short* hu = (unsigned short*)h;
  #pragma unroll
  for(int r=0; r<4; r++){
    int row = rowBase + w*16 + q*4 + r;
    float y[8]; float s = 0.f, sq = 0.f;
    #pragma unroll
    for(int nt=0; nt<8; nt++){
      float v = acc[nt][r] + blv[nt];
      y[nt] = v; s += v; sq += v*v;
    }
    #pragma unroll
    for(int off=1; off<16; off<<=1){ s += __shfl_xor(s, off); sq += __shfl_xor(sq, off); }
    float mu = s*(1.f/128.f);
    float var = fmaxf(sq*(1.f/128.f) - mu*mu, 0.f);
    float rstd = rsqrtf(var + 1e-5f);
    if(row < N){
      #pragma unroll
      for(int nt=0; nt<8; nt++){
        int col = nt*16 + p;
        float hv = bfu(hu[(size_t)row*128 + col]);
        float o = hv + fmaxf((y[nt]-mu)*rstd*gvv[nt] + bvv[nt], 0.f);
        hu[(size_t)row*128 + col] = (unsigned short)f2bf(o);
      }
    }
  }
}

// ---------------- fused both-heads via MFMA ----------------
// Stage1: y1[64 rows][256] = h @ [dW1|sW1]; relu+bias -> T1 (per-wave LDS, bf16)
// Stage2: y2[64][128] = T1d @ dW2 (n<64) / T1s @ sW2 (n>=64) via LDS A-frags
// Stage3: fp32 per-lane dots + 16-lane shfl reduce; out = (T2@W3 + b3)*ratio
__global__ __launch_bounds__(256) void k_heads_mfma(
  const bf16* __restrict__ h,
  const unsigned short* __restrict__ WT1,  // [256][128]
  const unsigned short* __restrict__ WT2,  // [128][128]
  const float* __restrict__ db1, const float* __restrict__ sb1,
  const float* __restrict__ db2, const float* __restrict__ sb2,
  const float* __restrict__ dW3, const float* __restrict__ db3,
  const float* __restrict__ sW3, const float* __restrict__ sb3,
  const float* __restrict__ ratio_p, float* __restrict__ out, int N)
{
  __shared__ __align__(16) unsigned short T1s[4][16][264];  // per-wave; 264=256+8 pad
  const float ratio = *ratio_p;
  int tid = threadIdx.x;
  int lane = tid & 63;
  int w = tid >> 6;
  int q = lane >> 4;
  int p = lane & 15;
  int rowBase = blockIdx.x*64;
  int am = rowBase + w*16 + p;
  bool arow_ok = am < N;
  const unsigned short* hRow = (const unsigned short*)h + (size_t)am*128;

  // ---- stage 1 ----
  f32x4 acc1[16];
  #pragma unroll
  for(int nt=0; nt<16; nt++) acc1[nt] = (f32x4){0.f,0.f,0.f,0.f};
  #pragma unroll
  for(int ks=0; ks<4; ks++){
    int koff = ks*32 + q*8;
    bf16x8 af = {0,0,0,0,0,0,0,0};
    if(arow_ok) af = *(const bf16x8*)(hRow + koff);
    #pragma unroll
    for(int nt=0; nt<16; nt++){
      bf16x8 bfr = *(const bf16x8*)(WT1 + (size_t)(nt*16+p)*128 + koff);
      acc1[nt] = __builtin_amdgcn_mfma_f32_16x16x32_bf16(af, bfr, acc1[nt], 0,0,0);
    }
  }
  #pragma unroll
  for(int nt=0; nt<16; nt++){
    float b1v = (nt<8) ? db1[nt*16+p] : sb1[(nt-8)*16+p];
    #pragma unroll
    for(int r=0;r<4;r++){
      float v = fmaxf(acc1[nt][r] + b1v, 0.f);
      T1s[w][q*4+r][nt*16+p] = (unsigned short)f2bf(v);
    }
  }
  __syncthreads();

  // ---- stage 2 ----
  f32x4 acc2[8];
  #pragma unroll
  for(int nt=0; nt<8; nt++) acc2[nt] = (f32x4){0.f,0.f,0.f,0.f};
  #pragma unroll
  for(int ks=0; ks<4; ks++){
    int koff = ks*32 + q*8;
    bf16x8 ad = *(const bf16x8*)&T1s[w][p][koff];        // disp T1 cols 0..127
    bf16x8 as = *(const bf16x8*)&T1s[w][p][128+koff];    // stress T1 cols 128..255
    #pragma unroll
    for(int nt=0; nt<8; nt++){
      bf16x8 bfr = *(const bf16x8*)(WT2 + (size_t)(nt*16+p)*128 + koff);
      acc2[nt] = __builtin_amdgcn_mfma_f32_16x16x32_bf16(nt<4? ad : as, bfr, acc2[nt], 0,0,0);
    }
  }

  // ---- stage 3 (fp32) ----
  float w3d[4][3], w3s[4], bd2[4], bs2[4];
  #pragma unroll
  for(int nt=0; nt<4; nt++){
    #pragma unroll
    for(int c=0;c<3;c++) w3d[nt][c] = dW3[(nt*16+p)*3 + c];
    w3s[nt] = sW3[nt*16+p];
    bd2[nt] = db2[nt*16+p];
    bs2[nt] = sb2[nt*16+p];
  }
  float b3v = (p==0)? db3[0] : (p==1)? db3[1] : (p==2)? db3[2] : sb3[0];
  #pragma unroll
  for(int r=0;r<4;r++){
    int row = rowBase + w*16 + q*4 + r;
    float pd0=0.f, pd1=0.f, pd2=0.f, ps=0.f;
    #pragma unroll
    for(int nt=0; nt<4; nt++){
      float td = fmaxf(acc2[nt][r]   + bd2[nt], 0.f);
      float ts = fmaxf(acc2[nt+4][r] + bs2[nt], 0.f);
      pd0 += td*w3d[nt][0]; pd1 += td*w3d[nt][1]; pd2 += td*w3d[nt][2];
      ps  += ts*w3s[nt];
    }
    #pragma unroll
    for(int off=1; off<16; off<<=1){
      pd0 += __shfl_xor(pd0, off); pd1 += __shfl_xor(pd1, off);
      pd2 += __shfl_xor(pd2, off); ps  += __shfl_xor(ps, off);
    }
    if(row < N && p < 4){
      float v = (p==0)? pd0 : (p==1)? pd1 : (p==2)? pd2 : ps;
      out[(size_t)row*4 + p] = (v + b3v)*ratio;
    }
  }
}

extern "C" void kernel_launch(void* const* d_in, const int* in_sizes, int n_in,
                              void* d_out, int out_size, void* d_ws, size_t ws_size,
                              hipStream_t stream)
{
  const float* x   = (const float*)d_in[0];
  const int*  eidx = (const int*) d_in[1];
  const float* eW1 = (const float*)d_in[2];
  const float* eb1 = (const float*)d_in[3];
  const float* eW2 = (const float*)d_in[4];
  const float* eb2 = (const float*)d_in[5];
  const float* llW = (const float*)d_in[6];
  const float* llb = (const float*)d_in[7];
  const float* lrW = (const float*)d_in[8];
  const float* lng = (const float*)d_in[9];
  const float* lnb = (const float*)d_in[10];
  const float* dW1 = (const float*)d_in[11];
  const float* db1 = (const float*)d_in[12];
  const float* dW2 = (const float*)d_in[13];
  const float* db2 = (const float*)d_in[14];
  const float* dW3 = (const float*)d_in[15];
  const float* db3 = (const float*)d_in[16];
  const float* sW1 = (const float*)d_in[17];
  const float* sb1 = (const float*)d_in[18];
  const float* sW2 = (const float*)d_in[19];
  const float* sb2 = (const float*)d_in[20];
  const float* sW3 = (const float*)d_in[21];
  const float* sb3 = (const float*)d_in[22];
  float* out = (float*)d_out;

  const int N = in_sizes[0] / 12;
  const int E = in_sizes[1] / 2;
  (void)n_in; (void)out_size; (void)ws_size;

  // workspace layout (256B aligned slots) — ~29.7 MB
  char* base = (char*)d_ws;
  size_t off = 0;
  auto alloc = [&](size_t nbytes)->char*{
    char* p = base + off; off += (nbytes + 255) & ~(size_t)255; return p;
  };
  unsigned* ratio = (unsigned*)alloc(4);
  int*   deg    = (int*)  alloc((size_t)N*4);
  int*   offs   = (int*)  alloc(((size_t)N+1)*4);
  int*   pos    = (int*)  alloc((size_t)N*4);
  int*   bsum   = (int*)  alloc(256*4);
  int*   csr    = (int*)  alloc((size_t)E*4);
  float* invdeg = (float*)alloc((size_t)N*4);
  bf16*  hA     = (bf16*) alloc((size_t)N*128*2);
  bf16*  agg    = (bf16*) alloc((size_t)N*128*2);
  unsigned short* WTs = (unsigned short*)alloc((size_t)4*128*256*2);  // sage W^T bf16
  unsigned short* WT1h = (unsigned short*)alloc((size_t)256*128*2);   // heads W1 cat
  unsigned short* WT2h = (unsigned short*)alloc((size_t)128*128*2);   // heads W2 cat

  size_t zbytes = (size_t)((char*)offs - base);   // zero ratio + deg
  hipMemsetAsync(d_ws, 0, zbytes, stream);

  int nbE    = (E + 255)/256;
  int nbScan = (N + 1023)/1024;
  int nbTile = (N + 63)/64;
  int nbAgg  = (N + 7)/8;

  k_ratio <<<256, 256, 0, stream>>>(x, ratio, N);
  k_degree<<<nbE, 256, 0, stream>>>(eidx, deg, E, N);
  k_scan1 <<<nbScan, 256, 0, stream>>>(deg, bsum, N);
  k_scan2 <<<1, 64, 0, stream>>>(bsum, nbScan);
  k_scan3 <<<nbScan, 256, 0, stream>>>(deg, bsum, offs, pos, invdeg, N, E);
  k_bucket<<<nbE, 256, 0, stream>>>(eidx, pos, csr, E, N);
  k_wconv <<<512, 256, 0, stream>>>(llW, lrW, WTs);
  k_wconv_heads<<<192, 256, 0, stream>>>(dW1, sW1, dW2, sW2, WT1h, WT2h);

  k_encoder<<<nbTile, 256, 0, stream>>>(x, eW1, eb1, eW2, eb2, hA, N);
  for(int l=0;l<4;l++){
    k_aggregate<<<nbAgg, 256, 0, stream>>>(hA, agg, offs, csr, invdeg, N, E);
    k_sage_mfma<<<nbTile, 256, 0, stream>>>(hA, agg,
        WTs + (size_t)l*128*256,
        llb + (size_t)l*128, lng + (size_t)l*128, lnb + (size_t)l*128, N);
  }
  k_heads_mfma<<<nbTile, 256, 0, stream>>>(hA, WT1h, WT2h,
      db1, sb1, db2, sb2, dW3, db3, sW3, sb3, (const float*)ratio, out, N);
}

// Round 7
// 390.393 us; speedup vs baseline: 3.4327x; 1.4163x over previous
//
#include <hip/hip_runtime.h>
#include <hip/hip_bf16.h>

typedef __hip_bfloat16 bf16;
typedef short bf16x8 __attribute__((ext_vector_type(8)));
typedef float f32x4 __attribute__((ext_vector_type(4)));

__device__ __forceinline__ float2 bfpair(unsigned u){
  float2 r; r.x = __uint_as_float(u<<16); r.y = __uint_as_float(u & 0xffff0000u); return r;
}
__device__ __forceinline__ float bfu(unsigned short u){ return __uint_as_float(((unsigned)u)<<16); }
__device__ __forceinline__ unsigned f2bf(float f){
  unsigned u = __float_as_uint(f);
  return (u + 0x7fffu + ((u>>16)&1u)) >> 16;
}
__device__ __forceinline__ unsigned fpack(float a, float b){
  return (f2bf(b)<<16) | f2bf(a);
}
__device__ __forceinline__ int edge_is64(const int* e){
  return (e[1]==0) & (e[3]==0) & (e[5]==0);
}
__device__ __forceinline__ int edge_ld(const int* e, int is64, int idx){
  return e[is64 ? 2*idx : idx];
}

// ---------------- fused prologue: blocks [0,nbE) degree histogram; rest ratio ------
__global__ void k_pre(const float* __restrict__ x, const int* __restrict__ eidx,
                      unsigned* __restrict__ ratio, int* __restrict__ deg,
                      int N, int E, int nbE){
  if((int)blockIdx.x < nbE){
    int e = blockIdx.x*blockDim.x + threadIdx.x;
    if(e>=E) return;
    int is64 = edge_is64(eidx);
    int d = edge_ld(eidx, is64, E+e);
    if((unsigned)d < (unsigned)N) atomicAdd(&deg[d], 1);
  } else {
    int i = (blockIdx.x-nbE)*blockDim.x + threadIdx.x;
    int stride = 256*blockDim.x;
    float m = 0.f;
    for(; i<N; i+=stride){
      float a = x[(size_t)i*12+3];
      float b = x[(size_t)i*12+4];
      float c = x[(size_t)i*12+5];
      m = fmaxf(m, sqrtf(a*a+b*b+c*c));
    }
    #pragma unroll
    for(int off=1; off<64; off<<=1) m = fmaxf(m, __shfl_xor(m, off));
    if((threadIdx.x & 63)==0) atomicMax(ratio, __float_as_uint(m));
  }
}

// ---------------- scan over deg[N]: block sums, wave-scan of sums, local scan ------
__global__ void k_scan1(const int* __restrict__ deg, int* __restrict__ bsum, int N){
  int t = threadIdx.x;
  int idx0 = blockIdx.x*1024 + t*4;
  int s=0;
  #pragma unroll
  for(int i=0;i<4;i++){ int idx=idx0+i; if(idx<N) s += deg[idx]; }
  #pragma unroll
  for(int off=1; off<64; off<<=1) s += __shfl_xor(s, off);
  __shared__ int ws4[4];
  if((t&63)==0) ws4[t>>6]=s;
  __syncthreads();
  if(t==0) bsum[blockIdx.x]=ws4[0]+ws4[1]+ws4[2]+ws4[3];
}
// nb <= 64: single-wave shfl exclusive scan (fallback: serial if nb>64)
__global__ void k_scan2w(int* bsum, int nb){
  int lane = threadIdx.x;
  if(nb <= 64){
    int v = (lane<nb)? bsum[lane] : 0;
    int incl = v;
    #pragma unroll
    for(int off=1; off<64; off<<=1){ int t = __shfl_up(incl, (unsigned)off); if(lane>=off) incl+=t; }
    if(lane<nb) bsum[lane] = incl - v;
  } else if(lane==0){
    int acc=0;
    for(int i=0;i<nb;i++){ int v=bsum[i]; bsum[i]=acc; acc+=v; }
  }
}
__global__ void k_scan3(const int* __restrict__ deg, const int* __restrict__ bsum,
                        int* __restrict__ offs, int* __restrict__ pos,
                        float* __restrict__ invdeg, int N, int E){
  int t = threadIdx.x;
  int idx0 = blockIdx.x*1024 + t*4;
  int d[4]; int s=0;
  #pragma unroll
  for(int i=0;i<4;i++){ int idx=idx0+i; d[i] = (idx<N)? deg[idx]:0; s+=d[i]; }
  int lane=t&63, w=t>>6;
  int incl=s;
  #pragma unroll
  for(int off=1; off<64; off<<=1){ int v=__shfl_up(incl, (unsigned)off); if(lane>=off) incl+=v; }
  __shared__ int wsum[4];
  if(lane==63) wsum[w]=incl;
  __syncthreads();
  int base = bsum[blockIdx.x];
  for(int i=0;i<w;i++) base += wsum[i];
  int run = base + incl - s;
  #pragma unroll
  for(int i=0;i<4;i++){
    int idx=idx0+i;
    if(idx<N){
      offs[idx]=run; pos[idx]=run;
      invdeg[idx] = 1.0f / (float)(d[i]>0? d[i]:1);
    }
    run += d[i];
  }
  if(blockIdx.x==0 && t==0) offs[N]=E;
}

// ---------------- bucket edges into CSR ----------------
__global__ void k_bucket(const int* __restrict__ eidx, int* __restrict__ pos,
                         int* __restrict__ csr, int E, int N){
  int e = blockIdx.x*blockDim.x + threadIdx.x;
  if(e>=E) return;
  int is64 = edge_is64(eidx);
  int d = edge_ld(eidx, is64, E+e);
  int s = edge_ld(eidx, is64, e);
  if((unsigned)d >= (unsigned)N) return;
  if((unsigned)s >= (unsigned)N) s = 0;
  int p = atomicAdd(&pos[d], 1);
  if((unsigned)p < (unsigned)E) csr[p] = s;
}

// ---------------- ALL weight conversions, MFMA-fragment-swizzled -------------------
// Fragment layout: frag[f][lane][j] — each B-load is one coalesced 1KB segment.
// lane=(q<<4)|p; element j: B[k = ks*32+q*8+j][n = nt*16+p].
// sage WTs:  l(4) x ks(8) x nt(8) x 64 x 8  = 131072   (k<128: Wl, else Wr)
// heads WT1: ks(4) x nt(16) x 64 x 8        =  32768   (n<128: dW1, else sW1)
// heads WT2: ks(4) x nt(8) x 64 x 8         =  16384   (n<64:  dW2, else sW2)
// enc WE2:   ks(4) x nt(8) x 64 x 8         =  16384
__global__ void k_wconv_all(
    const float* __restrict__ llW, const float* __restrict__ lrW,
    const float* __restrict__ dW1, const float* __restrict__ sW1,
    const float* __restrict__ dW2, const float* __restrict__ sW2,
    const float* __restrict__ eW2,
    unsigned short* __restrict__ WTs, unsigned short* __restrict__ WT1,
    unsigned short* __restrict__ WT2, unsigned short* __restrict__ WE2){
  int idx = blockIdx.x*256 + threadIdx.x;   // 196608 total
  int j = idx & 7;
  int lane = (idx>>3) & 63;
  int q = lane >> 4, p = lane & 15;
  if(idx < 131072){
    int nt = (idx>>9) & 7, ks = (idx>>12) & 7, l = (idx>>15) & 3;
    int k = ks*32 + q*8 + j, n = nt*16 + p;
    float v = (k<128) ? llW[(size_t)l*16384 + (size_t)k*128 + n]
                      : lrW[(size_t)l*16384 + (size_t)(k-128)*128 + n];
    WTs[idx] = (unsigned short)f2bf(v);
  } else if(idx < 163840){
    int i2 = idx - 131072;
    int nt = (i2>>9) & 15, ks = (i2>>13) & 3;
    int k = ks*32 + q*8 + j, n = nt*16 + p;
    float v = (n<128) ? dW1[(size_t)k*128 + n] : sW1[(size_t)k*128 + (n-128)];
    WT1[i2] = (unsigned short)f2bf(v);
  } else if(idx < 180224){
    int i2 = idx - 163840;
    int nt = (i2>>9) & 7, ks = (i2>>12) & 3;
    int k = ks*32 + q*8 + j, n = nt*16 + p;
    float v = (n<64) ? dW2[(size_t)k*64 + n] : sW2[(size_t)k*64 + (n-64)];
    WT2[i2] = (unsigned short)f2bf(v);
  } else if(idx < 196608){
    int i2 = idx - 180224;
    int nt = (i2>>9) & 7, ks = (i2>>12) & 3;
    int k = ks*32 + q*8 + j, n = nt*16 + p;
    WE2[i2] = (unsigned short)f2bf(eW2[(size_t)k*128 + n]);
  }
}

// ---------------- mean aggregation: half-wave (32 lanes) per dst row ----------------
__global__ __launch_bounds__(256) void k_aggregate(
    const bf16* __restrict__ h, bf16* __restrict__ agg,
    const int* __restrict__ offs, const int* __restrict__ csr,
    const float* __restrict__ invdeg, int N, int E){
  int row = blockIdx.x*8 + (threadIdx.x>>5);
  int l = threadIdx.x & 31;
  if(row >= N) return;
  int s = offs[row], e = offs[row+1];
  s = max(0, min(s, E)); e = max(s, min(e, E));
  float a0=0.f, a1=0.f, a2=0.f, a3=0.f;
  int i = s;
  for(; i+4<=e; i+=4){
    int j0=csr[i], j1=csr[i+1], j2=csr[i+2], j3=csr[i+3];
    uint2 u0 = *(const uint2*)(h + (size_t)j0*128 + l*4);
    uint2 u1 = *(const uint2*)(h + (size_t)j1*128 + l*4);
    uint2 u2 = *(const uint2*)(h + (size_t)j2*128 + l*4);
    uint2 u3 = *(const uint2*)(h + (size_t)j3*128 + l*4);
    float2 p0=bfpair(u0.x), q0=bfpair(u0.y);
    float2 p1=bfpair(u1.x), q1=bfpair(u1.y);
    float2 p2=bfpair(u2.x), q2=bfpair(u2.y);
    float2 p3=bfpair(u3.x), q3=bfpair(u3.y);
    a0 += p0.x+p1.x+p2.x+p3.x;
    a1 += p0.y+p1.y+p2.y+p3.y;
    a2 += q0.x+q1.x+q2.x+q3.x;
    a3 += q0.y+q1.y+q2.y+q3.y;
  }
  for(; i<e; ++i){
    int j = csr[i];
    uint2 u = *(const uint2*)(h + (size_t)j*128 + l*4);
    float2 p=bfpair(u.x), q=bfpair(u.y);
    a0+=p.x; a1+=p.y; a2+=q.x; a3+=q.y;
  }
  float id = invdeg[row];
  uint2 o; o.x = fpack(a0*id, a1*id); o.y = fpack(a2*id, a3*id);
  *(uint2*)(agg + (size_t)row*128 + l*4) = o;
}

// ---------------- encoder: stage1 VALU (K=12) -> bf16 LDS; stage2 MFMA -------------
__global__ __launch_bounds__(256) void k_encoder(
  const float* __restrict__ x,
  const float* __restrict__ W1, const float* __restrict__ b1,
  const unsigned short* __restrict__ WE2, const float* __restrict__ b2,
  bf16* __restrict__ h, int N)
{
  __shared__ float Xs[64][12];
  __shared__ float W1s[12][128];
  __shared__ float b1s[128];
  __shared__ __align__(16) unsigned short T1b[64][136];
  int tid = threadIdx.x;
  int tx = tid & 31, ty = tid >> 5;
  int rowBase = blockIdx.x*64;
  for(int idx=tid; idx<768; idx+=256){
    int r = idx/12, c = idx - r*12;
    int row = rowBase + r;
    Xs[r][c] = (row<N)? x[(size_t)row*12+c] : 0.f;
  }
  for(int idx=tid; idx<1536; idx+=256) W1s[idx>>7][idx&127] = W1[idx];
  if(tid<128) b1s[tid] = b1[tid];
  __syncthreads();
  float acc[8][4] = {};
  #pragma unroll
  for(int k=0;k<12;k++){
    float4 w4 = *(float4*)&W1s[k][tx*4];
    #pragma unroll
    for(int r=0;r<8;r++){
      float a = Xs[ty*8+r][k];
      acc[r][0]+=a*w4.x; acc[r][1]+=a*w4.y; acc[r][2]+=a*w4.z; acc[r][3]+=a*w4.w;
    }
  }
  #pragma unroll
  for(int r=0;r<8;r++)
    #pragma unroll
    for(int c=0;c<4;c++)
      T1b[ty*8+r][tx*4+c] = (unsigned short)f2bf(fmaxf(acc[r][c] + b1s[tx*4+c], 0.f));
  __syncthreads();

  // stage 2: h = T1 @ W2 + b2 via MFMA
  int lane = tid & 63;
  int w = tid >> 6, q = lane >> 4, p = lane & 15;
  f32x4 acc2[8];
  #pragma unroll
  for(int nt=0; nt<8; nt++) acc2[nt] = (f32x4){0.f,0.f,0.f,0.f};
  #pragma unroll
  for(int ks=0; ks<4; ks++){
    bf16x8 af = *(const bf16x8*)&T1b[w*16+p][ks*32+q*8];
    #pragma unroll
    for(int nt=0; nt<8; nt++){
      bf16x8 bfr = *(const bf16x8*)(WE2 + ((size_t)(ks*8+nt)*64 + lane)*8);
      acc2[nt] = __builtin_amdgcn_mfma_f32_16x16x32_bf16(af, bfr, acc2[nt], 0,0,0);
    }
  }
  float b2v[8];
  #pragma unroll
  for(int nt=0; nt<8; nt++) b2v[nt] = b2[nt*16+p];
  unsigned short* hu = (unsigned short*)h;
  #pragma unroll
  for(int r=0;r<4;r++){
    int row = rowBase + w*16 + q*4 + r;
    if(row < N){
      #pragma unroll
      for(int nt=0; nt<8; nt++)
        hu[(size_t)row*128 + nt*16+p] = (unsigned short)f2bf(acc2[nt][r] + b2v[nt]);
    }
  }
}

// ---------------- SAGE layer via MFMA, swizzled B frags ----------------
__global__ __launch_bounds__(256) void k_sage_mfma(
    bf16* __restrict__ h, const bf16* __restrict__ agg,
    const unsigned short* __restrict__ WT,   // swizzled frags: [ks8][nt8][64][8]
    const float* __restrict__ bl, const float* __restrict__ lng,
    const float* __restrict__ lnb, int N)
{
  int tid = threadIdx.x;
  int lane = tid & 63;
  int w = tid >> 6;
  int q = lane >> 4;
  int p = lane & 15;
  int rowBase = blockIdx.x*64;

  int am = rowBase + w*16 + p;
  bool arow_ok = am < N;
  const unsigned short* aggRow = (const unsigned short*)agg + (size_t)am*128;
  const unsigned short* hRow   = (const unsigned short*)h   + (size_t)am*128;

  f32x4 acc[8];
  #pragma unroll
  for(int nt=0; nt<8; nt++) acc[nt] = (f32x4){0.f,0.f,0.f,0.f};

  #pragma unroll
  for(int ks=0; ks<8; ks++){
    int koff = ks*32 + q*8;
    bf16x8 afrag = {0,0,0,0,0,0,0,0};
    if(arow_ok){
      const unsigned short* src = (koff < 128) ? (aggRow + koff) : (hRow + (koff-128));
      afrag = *(const bf16x8*)src;
    }
    #pragma unroll
    for(int nt=0; nt<8; nt++){
      bf16x8 bfrag = *(const bf16x8*)(WT + ((size_t)(ks*8+nt)*64 + lane)*8);
      acc[nt] = __builtin_amdgcn_mfma_f32_16x16x32_bf16(afrag, bfrag, acc[nt], 0, 0, 0);
    }
  }

  float blv[8], gvv[8], bvv[8];
  #pragma unroll
  for(int nt=0; nt<8; nt++){
    int col = nt*16 + p;
    blv[nt] = bl[col]; gvv[nt] = lng[col]; bvv[nt] = lnb[col];
  }
  unsigned short* hu = (unsigned short*)h;
  #pragma unroll
  for(int r=0; r<4; r++){
    int row = rowBase + w*16 + q*4 + r;
    float y[8]; float s = 0.f, sq = 0.f;
    #pragma unroll
    for(int nt=0; nt<8; nt++){
      float v = acc[nt][r] + blv[nt];
      y[nt] = v; s += v; sq += v*v;
    }
    #pragma unroll
    for(int off=1; off<16; off<<=1){ s += __shfl_xor(s, off); sq += __shfl_xor(sq, off); }
    float mu = s*(1.f/128.f);
    float var = fmaxf(sq*(1.f/128.f) - mu*mu, 0.f);
    float rstd = rsqrtf(var + 1e-5f);
    if(row < N){
      #pragma unroll
      for(int nt=0; nt<8; nt++){
        int col = nt*16 + p;
        float hv = bfu(hu[(size_t)row*128 + col]);
        float o = hv + fmaxf((y[nt]-mu)*rstd*gvv[nt] + bvv[nt], 0.f);
        hu[(size_t)row*128 + col] = (unsigned short)f2bf(o);
      }
    }
  }
}

// ---------------- fused both-heads via MFMA, swizzled B frags ----------------
__global__ __launch_bounds__(256) void k_heads_mfma(
  const bf16* __restrict__ h,
  const unsigned short* __restrict__ WT1,  // [ks4][nt16][64][8]
  const unsigned short* __restrict__ WT2,  // [ks4][nt8][64][8]
  const float* __restrict__ db1, const float* __restrict__ sb1,
  const float* __restrict__ db2, const float* __restrict__ sb2,
  const float* __restrict__ dW3, const float* __restrict__ db3,
  const float* __restrict__ sW3, const float* __restrict__ sb3,
  const float* __restrict__ ratio_p, float* __restrict__ out, int N)
{
  __shared__ __align__(16) unsigned short T1s[4][16][264];
  const float ratio = *ratio_p;
  int tid = threadIdx.x;
  int lane = tid & 63;
  int w = tid >> 6;
  int q = lane >> 4;
  int p = lane & 15;
  int rowBase = blockIdx.x*64;
  int am = rowBase + w*16 + p;
  bool arow_ok = am < N;
  const unsigned short* hRow = (const unsigned short*)h + (size_t)am*128;

  // ---- stage 1 ----
  f32x4 acc1[16];
  #pragma unroll
  for(int nt=0; nt<16; nt++) acc1[nt] = (f32x4){0.f,0.f,0.f,0.f};
  #pragma unroll
  for(int ks=0; ks<4; ks++){
    int koff = ks*32 + q*8;
    bf16x8 af = {0,0,0,0,0,0,0,0};
    if(arow_ok) af = *(const bf16x8*)(hRow + koff);
    #pragma unroll
    for(int nt=0; nt<16; nt++){
      bf16x8 bfr = *(const bf16x8*)(WT1 + ((size_t)(ks*16+nt)*64 + lane)*8);
      acc1[nt] = __builtin_amdgcn_mfma_f32_16x16x32_bf16(af, bfr, acc1[nt], 0,0,0);
    }
  }
  #pragma unroll
  for(int nt=0; nt<16; nt++){
    float b1v = (nt<8) ? db1[nt*16+p] : sb1[(nt-8)*16+p];
    #pragma unroll
    for(int r=0;r<4;r++){
      float v = fmaxf(acc1[nt][r] + b1v, 0.f);
      T1s[w][q*4+r][nt*16+p] = (unsigned short)f2bf(v);
    }
  }
  __syncthreads();

  // ---- stage 2 ----
  f32x4 acc2[8];
  #pragma unroll
  for(int nt=0; nt<8; nt++) acc2[nt] = (f32x4){0.f,0.f,0.f,0.f};
  #pragma unroll
  for(int ks=0; ks<4; ks++){
    int koff = ks*32 + q*8;
    bf16x8 ad = *(const bf16x8*)&T1s[w][p][koff];
    bf16x8 as = *(const bf16x8*)&T1s[w][p][128+koff];
    #pragma unroll
    for(int nt=0; nt<8; nt++){
      bf16x8 bfr = *(const bf16x8*)(WT2 + ((size_t)(ks*8+nt)*64 + lane)*8);
      acc2[nt] = __builtin_amdgcn_mfma_f32_16x16x32_bf16(nt<4? ad : as, bfr, acc2[nt], 0,0,0);
    }
  }

  // ---- stage 3 (fp32) ----
  float w3d[4][3], w3s[4], bd2[4], bs2[4];
  #pragma unroll
  for(int nt=0; nt<4; nt++){
    #pragma unroll
    for(int c=0;c<3;c++) w3d[nt][c] = dW3[(nt*16+p)*3 + c];
    w3s[nt] = sW3[nt*16+p];
    bd2[nt] = db2[nt*16+p];
    bs2[nt] = sb2[nt*16+p];
  }
  float b3v = (p==0)? db3[0] : (p==1)? db3[1] : (p==2)? db3[2] : sb3[0];
  #pragma unroll
  for(int r=0;r<4;r++){
    int row = rowBase + w*16 + q*4 + r;
    float pd0=0.f, pd1=0.f, pd2=0.f, ps=0.f;
    #pragma unroll
    for(int nt=0; nt<4; nt++){
      float td = fmaxf(acc2[nt][r]   + bd2[nt], 0.f);
      float ts = fmaxf(acc2[nt+4][r] + bs2[nt], 0.f);
      pd0 += td*w3d[nt][0]; pd1 += td*w3d[nt][1]; pd2 += td*w3d[nt][2];
      ps  += ts*w3s[nt];
    }
    #pragma unroll
    for(int off=1; off<16; off<<=1){
      pd0 += __shfl_xor(pd0, off); pd1 += __shfl_xor(pd1, off);
      pd2 += __shfl_xor(pd2, off); ps  += __shfl_xor(ps, off);
    }
    if(row < N && p < 4){
      float v = (p==0)? pd0 : (p==1)? pd1 : (p==2)? pd2 : ps;
      out[(size_t)row*4 + p] = (v + b3v)*ratio;
    }
  }
}

extern "C" void kernel_launch(void* const* d_in, const int* in_sizes, int n_in,
                              void* d_out, int out_size, void* d_ws, size_t ws_size,
                              hipStream_t stream)
{
  const float* x   = (const float*)d_in[0];
  const int*  eidx = (const int*) d_in[1];
  const float* eW1 = (const float*)d_in[2];
  const float* eb1 = (const float*)d_in[3];
  const float* eW2 = (const float*)d_in[4];
  const float* eb2 = (const float*)d_in[5];
  const float* llW = (const float*)d_in[6];
  const float* llb = (const float*)d_in[7];
  const float* lrW = (const float*)d_in[8];
  const float* lng = (const float*)d_in[9];
  const float* lnb = (const float*)d_in[10];
  const float* dW1 = (const float*)d_in[11];
  const float* db1 = (const float*)d_in[12];
  const float* dW2 = (const float*)d_in[13];
  const float* db2 = (const float*)d_in[14];
  const float* dW3 = (const float*)d_in[15];
  const float* db3 = (const float*)d_in[16];
  const float* sW1 = (const float*)d_in[17];
  const float* sb1 = (const float*)d_in[18];
  const float* sW2 = (const float*)d_in[19];
  const float* sb2 = (const float*)d_in[20];
  const float* sW3 = (const float*)d_in[21];
  const float* sb3 = (const float*)d_in[22];
  float* out = (float*)d_out;

  const int N = in_sizes[0] / 12;
  const int E = in_sizes[1] / 2;
  (void)n_in; (void)out_size; (void)ws_size;

  char* base = (char*)d_ws;
  size_t off = 0;
  auto alloc = [&](size_t nbytes)->char*{
    char* p = base + off; off += (nbytes + 255) & ~(size_t)255; return p;
  };
  unsigned* ratio = (unsigned*)alloc(4);
  int*   deg    = (int*)  alloc((size_t)N*4);
  int*   offs   = (int*)  alloc(((size_t)N+1)*4);
  int*   pos    = (int*)  alloc((size_t)N*4);
  int*   bsum   = (int*)  alloc(256*4);
  int*   csr    = (int*)  alloc((size_t)E*4);
  float* invdeg = (float*)alloc((size_t)N*4);
  bf16*  hA     = (bf16*) alloc((size_t)N*128*2);
  bf16*  agg    = (bf16*) alloc((size_t)N*128*2);
  unsigned short* WTs  = (unsigned short*)alloc((size_t)131072*2);
  unsigned short* WT1h = (unsigned short*)alloc((size_t)32768*2);
  unsigned short* WT2h = (unsigned short*)alloc((size_t)16384*2);
  unsigned short* WE2  = (unsigned short*)alloc((size_t)16384*2);

  size_t zbytes = (size_t)((char*)offs - base);   // zero ratio + deg
  hipMemsetAsync(d_ws, 0, zbytes, stream);

  int nbE    = (E + 255)/256;
  int nbScan = (N + 1023)/1024;
  int nbTile = (N + 63)/64;
  int nbAgg  = (N + 7)/8;

  k_pre   <<<nbE + 256, 256, 0, stream>>>(x, eidx, ratio, deg, N, E, nbE);
  k_scan1 <<<nbScan, 256, 0, stream>>>(deg, bsum, N);
  k_scan2w<<<1, 64, 0, stream>>>(bsum, nbScan);
  k_scan3 <<<nbScan, 256, 0, stream>>>(deg, bsum, offs, pos, invdeg, N, E);
  k_bucket<<<nbE, 256, 0, stream>>>(eidx, pos, csr, E, N);
  k_wconv_all<<<768, 256, 0, stream>>>(llW, lrW, dW1, sW1, dW2, sW2, eW2,
                                       WTs, WT1h, WT2h, WE2);

  k_encoder<<<nbTile, 256, 0, stream>>>(x, eW1, eb1, WE2, eb2, hA, N);
  for(int l=0;l<4;l++){
    k_aggregate<<<nbAgg, 256, 0, stream>>>(hA, agg, offs, csr, invdeg, N, E);
    k_sage_mfma<<<nbTile, 256, 0, stream>>>(hA, agg,
        WTs + (size_t)l*32768,
        llb + (size_t)l*128, lng + (size_t)l*128, lnb + (size_t)l*128, N);
  }
  k_heads_mfma<<<nbTile, 256, 0, stream>>>(hA, WT1h, WT2h,
      db1, sb1, db2, sb2, dW3, db3, sW3, sb3, (const float*)ratio, out, N);
}